// Round 4
// baseline (670.968 us; speedup 1.0000x reference)
//
#include <hip/hip_runtime.h>
#include <math.h>

// ---------------- workspace layout (bytes unless _F) ----------------
#define WS_M1_F    0           // 4096 f32
#define WS_M2_F    4096        // 4096 f32
#define WS_BNSC_F  8192        // 64 f32
#define WS_BNSH_F  8256        // 64 f32
#define WS_WT_F    8448        // 12288 f32 (conv_w transposed [ik][o])
#define OFF_W1T    83968       // u16[32*2048]  attn_w1^T fp16  -> +131072 = 215040
#define OFF_CW1H   215040      // u16[128*2048] cls_w1^T bf16-hi -> +524288 = 739328
#define OFF_CW1L   739328      // u16[128*2048] cls_w1^T bf16-lo -> +524288 = 1263616
#define OFF_CTX    1263616     // per-chunk ctx hi/lo planes (8192 B/batch)

typedef _Float16 v8h __attribute__((ext_vector_type(8)));
typedef short v8s __attribute__((ext_vector_type(8)));
typedef float v4f __attribute__((ext_vector_type(4)));
typedef float v16f __attribute__((ext_vector_type(16)));

__device__ __forceinline__ unsigned short f2h_u(float x) {
  _Float16 h = (_Float16)x;
  union { _Float16 h; unsigned short u; } v; v.h = h; return v.u;
}
__device__ __forceinline__ unsigned short bf16t(float x) {
  union { float f; unsigned int u; } v; v.f = x; return (unsigned short)(v.u >> 16);
}
__device__ __forceinline__ float bf16tof(unsigned short s) {
  union { unsigned int u; float f; } v; v.u = ((unsigned int)s) << 16; return v.f;
}

// ================= K1: prep (multi-block) =================
__global__ __launch_bounds__(256) void k_prep(
    const float* __restrict__ mask1, const float* __restrict__ mask2,
    const float* __restrict__ conv_w, const float* __restrict__ conv_b,
    const float* __restrict__ bn_gamma, const float* __restrict__ bn_beta,
    const float* __restrict__ bn_mean, const float* __restrict__ bn_var,
    const float* __restrict__ attn_w1, const float* __restrict__ cls_w1,
    float* __restrict__ wsf, unsigned short* __restrict__ w1t,
    unsigned short* __restrict__ cw1h, unsigned short* __restrict__ cw1l)
{
  const int gid = blockIdx.x * 256 + threadIdx.x;
  const int gsz = gridDim.x * 256;
  float* m1 = wsf + WS_M1_F;
  float* m2 = wsf + WS_M2_F;
  float* bnsc = wsf + WS_BNSC_F;
  float* bnsh = wsf + WS_BNSH_F;
  float* wT = wsf + WS_WT_F;
  for (int e = gid; e < 4096; e += gsz) {
    int i = e >> 6, j = e & 63;
    float s1 = mask1[e] + mask1[j * 64 + i];
    float s2 = mask2[e] + mask2[j * 64 + i];
    m1[e] = 0.5f / (1.f + expf(-s1));
    m2[e] = 0.5f / (1.f + expf(-s2));
  }
  for (int e = gid; e < 64; e += gsz) {
    float sc = bn_gamma[e] * rsqrtf(bn_var[e] + 1e-5f);
    bnsc[e] = sc;
    bnsh[e] = (conv_b[e] - bn_mean[e]) * sc + bn_beta[e];
  }
  for (int e = gid; e < 12288; e += gsz) {
    int o = e / 192, ik = e % 192;
    wT[ik * 64 + o] = conv_w[e];
  }
  // attn_w1^T: read coalesced (f consecutive == source consecutive), write scattered
  for (int f = gid; f < 65536; f += gsz) {
    int i = f >> 5, n = f & 31;
    w1t[n * 2048 + i] = f2h_u(attn_w1[f]);
  }
  // cls_w1^T hi/lo: read coalesced, write scattered
  for (int f = gid; f < 262144; f += gsz) {
    int k = f >> 7, n = f & 127;
    float x = cls_w1[f];
    unsigned short h = bf16t(x);
    cw1h[n * 2048 + k] = h;
    cw1l[n * 2048 + k] = bf16t(x - bf16tof(h));
  }
}

// ===== K2: fused conv+BN -> recurrence -> attention, one block per batch =====
// 512 threads (8 waves). LDS: pots_s 65536 B + smR 11776 B = 77312 B
// -> 2 blocks/CU (154624 <= 163840), 16 waves/CU.
// Phase C (recurrence) uses waves 0-3 with the proven 4-wave structure;
// waves 4-7 participate only in barriers and in phases A/D (split 8-ways).
__global__ __launch_bounds__(512) void k_fused(
    const float* __restrict__ L_norm, const float* __restrict__ X_seq,
    const float* __restrict__ gcn1_w, const float* __restrict__ gcn1_b,
    const float* __restrict__ gcn2_w, const float* __restrict__ gcn2_b,
    const float* __restrict__ beta2p, const float* __restrict__ wsf,
    const unsigned short* __restrict__ w1t,
    const float* __restrict__ attn_b1, const float* __restrict__ attn_w2,
    const float* __restrict__ attn_b2,
    unsigned short* __restrict__ ctxh, unsigned short* __restrict__ ctxl,
    int b0)
{
  __shared__ __align__(16) unsigned short pots_s[16 * 2048];
  __shared__ __align__(16) char smR[11776];
  float* xcur = (float*)smR;                          // 960 f32   [0,3840)
  float* zp = (float*)(smR + 3840);                   // 128 f32   [3840,4352)
  unsigned short* spk1T = (unsigned short*)(smR + 4352); // 16*72 u16 [4352,6656)
  float* Z2f = (float*)(smR + 6656);                  // 64*20 f32 [6656,11776)

  const int tid = threadIdx.x;
  const int lane = tid & 63;
  const int wv = tid >> 6;
  const int b = b0 + blockIdx.x;

  const float* m1 = wsf + WS_M1_F;
  const float* m2 = wsf + WS_M2_F;

  // ---- phase A: conv + BN. xraw + wT staged into pots_s (dead region) ----
  {
    float* xraw = (float*)pots_s;            // bytes [0,3840)
    float* wTl = (float*)(pots_s + 2048);    // bytes [4096,53248)
    for (int e = tid; e < 960; e += 512) xraw[e] = X_seq[(size_t)b * 960 + e];
    {
      const float* wT = wsf + WS_WT_F;
      for (int e = tid; e < 12288; e += 512) wTl[e] = wT[e];
    }
    // zero pots_s row 15 (bytes [61440,65536)): feeds discarded t=15 MFMA row
    if (tid < 256) *(uint4*)&pots_s[15 * 2048 + tid * 8] = make_uint4(0u, 0u, 0u, 0u);
    __syncthreads();
    const float* bnsc = wsf + WS_BNSC_F;
    const float* bnsh = wsf + WS_BNSH_F;
    const int o = lane;
    const float sc = bnsc[o], sh = bnsh[o];
    for (int tt = wv; tt < 15; tt += 8) {
      float a = 0.f;
      for (int i = 0; i < 64; ++i) {
        const float w0 = wTl[(3 * i + 0) * 64 + o];
        const float w1 = wTl[(3 * i + 1) * 64 + o];
        const float w2 = wTl[(3 * i + 2) * 64 + o];
        float xa = (tt >= 2) ? xraw[(tt - 2) * 64 + i] : 0.f;
        float xb = (tt >= 1) ? xraw[(tt - 1) * 64 + i] : 0.f;
        a += w0 * xa + w1 * xb + w2 * xraw[tt * 64 + i];
      }
      xcur[tt * 64 + o] = a * sc + sh;
    }
    __syncthreads();
  }

  // ---- phase B: register prep (waves 0-3 only) ----
  float L1h[32];
  const int kb1 = (wv & 1) * 32;
  if (wv == 2 || wv == 3) {
    const float* Lb = L_norm + (size_t)b * 4096 + lane * 64 + kb1;
    const float* mr = m1 + lane * 64 + kb1;
#pragma unroll
    for (int q4 = 0; q4 < 8; ++q4) {
      float4 lv = *(const float4*)(Lb + 4 * q4);
      float4 mv = *(const float4*)(mr + 4 * q4);
      L1h[4 * q4 + 0] = lv.x * mv.x;
      L1h[4 * q4 + 1] = lv.y * mv.y;
      L1h[4 * q4 + 2] = lv.z * mv.z;
      L1h[4 * q4 + 3] = lv.w * mv.w;
    }
  }

  v8s A_hi[2], A_lo[2];
  if (wv < 4) {
    const int irow = wv * 16 + (lane & 15);
    const int quad = (lane >> 4) & 3;
#pragma unroll
    for (int kb = 0; kb < 2; ++kb) {
      const float* Lb = L_norm + (size_t)b * 4096 + irow * 64 + kb * 32 + quad * 8;
      const float* mr = m2 + irow * 64 + kb * 32 + quad * 8;
      float4 la = *(const float4*)Lb, lb2 = *(const float4*)(Lb + 4);
      float4 ma = *(const float4*)mr, mb = *(const float4*)(mr + 4);
      float v[8] = { la.x * ma.x, la.y * ma.y, la.z * ma.z, la.w * ma.w,
                     lb2.x * mb.x, lb2.y * mb.y, lb2.z * mb.z, lb2.w * mb.w };
#pragma unroll
      for (int e = 0; e < 8; ++e) {
        unsigned short h = bf16t(v[e]);
        unsigned short l = bf16t(v[e] - bf16tof(h));
        A_hi[kb][e] = (short)h;
        A_lo[kb][e] = (short)l;
      }
    }
  }

  v8s W_hi, W_lo;
  if (wv < 2) {
    const int n = lane & 31;
    const int kh = (lane >> 5) & 1;
#pragma unroll
    for (int e = 0; e < 8; ++e) {
      float x = gcn2_w[(kh * 8 + e) * 32 + n];
      unsigned short h = bf16t(x);
      unsigned short l = bf16t(x - bf16tof(h));
      W_hi[e] = (short)h;
      W_lo[e] = (short)l;
    }
  }

  const float b2h = gcn2_b[lane & 31];
  const int np = (tid & 255) >> 3;
  const int cp = tid & 7;
  float w1c[2], b1c[2];
#pragma unroll
  for (int d = 0; d < 2; ++d) { w1c[d] = gcn1_w[2 * cp + d]; b1c[d] = gcn1_b[2 * cp + d]; }
  const float beta2 = beta2p[0];

  float mem_t = 0.f;
  float mg1[4] = {0.f, 0.f, 0.f, 0.f};
  v16f mg2;
#pragma unroll
  for (int r = 0; r < 16; ++r) mg2[r] = 0.f;

  auto stage_b = [&](int tm1) {
    const int m = lane & 31;
    const int half = lane >> 5;
    const float* zr = Z2f + (wv * 32 + m) * 20 + half * 8;
    float4 za = *(const float4*)zr;
    float4 zb = *(const float4*)(zr + 4);
    float vv[8] = {za.x, za.y, za.z, za.w, zb.x, zb.y, zb.z, zb.w};
    v8s Ah, Al;
#pragma unroll
    for (int e = 0; e < 8; ++e) {
      unsigned short h = bf16t(vv[e]);
      unsigned short l = bf16t(vv[e] - bf16tof(h));
      Ah[e] = (short)h;
      Al[e] = (short)l;
    }
    v16f acc;
#pragma unroll
    for (int r = 0; r < 16; ++r) {
      float rs = (mg2[r] > 1.f) ? 1.f : 0.f;
      acc[r] = fmaf(beta2, mg2[r], b2h - rs);
    }
    acc = __builtin_amdgcn_mfma_f32_32x32x16_bf16(Ah, W_hi, acc, 0, 0, 0);
    acc = __builtin_amdgcn_mfma_f32_32x32x16_bf16(Al, W_hi, acc, 0, 0, 0);
    acc = __builtin_amdgcn_mfma_f32_32x32x16_bf16(Ah, W_lo, acc, 0, 0, 0);
    mg2 = acc;
    const int xorv = (tm1 & 7) << 3;
    const int base = tm1 * 2048 + m;
#pragma unroll
    for (int r = 0; r < 16; ++r) {
      int i = wv * 32 + (r & 3) + 8 * (r >> 2) + 4 * half;
      pots_s[(base + i * 32) ^ xorv] = f2h_u(acc[r]);
    }
  };

  // ---- phase C: 15-step recurrence (waves 0-3; waves 4-7 barrier-only) ----
  for (int t = 0; t < 15; ++t) {
    if (wv == 2 || wv == 3) {
      float xc = xcur[t * 64 + lane];
      float rs = (mem_t > 1.f) ? 1.f : 0.f;
      mem_t = 0.9f * mem_t + xc - rs;
      float sp = (mem_t > 1.f) ? 1.f : 0.f;
      int spi = __float_as_int(sp);
      float zh = 0.f;
#pragma unroll
      for (int k = 0; k < 32; ++k) {
        float s = __int_as_float(__builtin_amdgcn_readlane(spi, kb1 + k));
        zh = fmaf(s, L1h[k], zh);
      }
      zp[(wv & 1) * 64 + lane] = zh;
    } else if (wv < 2 && t > 0) {
      stage_b(t - 1);
    }
    __syncthreads();
    if (tid < 256) {
      float2 q0 = *(const float2*)&zp[2 * np];
      float2 q1 = *(const float2*)&zp[64 + 2 * np];
      float z0 = q0.x + q1.x;
      float z1v = q0.y + q1.y;
#pragma unroll
      for (int d = 0; d < 2; ++d) {
        float cur0 = fmaf(z0, w1c[d], b1c[d]);
        float rs0 = (mg1[d * 2 + 0] > 1.f) ? 1.f : 0.f;
        mg1[d * 2 + 0] = 0.85f * mg1[d * 2 + 0] + cur0 - rs0;
        unsigned int bits0 = (mg1[d * 2 + 0] > 1.f) ? 0x3F80u : 0u;
        float cur1 = fmaf(z1v, w1c[d], b1c[d]);
        float rs1 = (mg1[d * 2 + 1] > 1.f) ? 1.f : 0.f;
        mg1[d * 2 + 1] = 0.85f * mg1[d * 2 + 1] + cur1 - rs1;
        unsigned int bits1 = (mg1[d * 2 + 1] > 1.f) ? 0x3F80u : 0u;
        *(unsigned int*)&spk1T[(2 * cp + d) * 72 + 2 * np] = bits0 | (bits1 << 16);
      }
    }
    __syncthreads();
    if (wv < 4) {
      const int c = lane & 15;
      const int quad = (lane >> 4) & 3;
      const unsigned short* bp = spk1T + c * 72 + quad * 8;
      v8s B0 = *(const v8s*)(bp);
      v8s B1 = *(const v8s*)(bp + 32);
      v4f acc = {0.f, 0.f, 0.f, 0.f};
      acc = __builtin_amdgcn_mfma_f32_16x16x32_bf16(A_hi[0], B0, acc, 0, 0, 0);
      acc = __builtin_amdgcn_mfma_f32_16x16x32_bf16(A_lo[0], B0, acc, 0, 0, 0);
      acc = __builtin_amdgcn_mfma_f32_16x16x32_bf16(A_hi[1], B1, acc, 0, 0, 0);
      acc = __builtin_amdgcn_mfma_f32_16x16x32_bf16(A_lo[1], B1, acc, 0, 0, 0);
      const int r0 = wv * 16 + quad * 4;
#pragma unroll
      for (int r = 0; r < 4; ++r) Z2f[(r0 + r) * 20 + c] = acc[r];
    }
    __syncthreads();
  }
  if (wv < 2) stage_b(14);
  __syncthreads();   // pots_s complete; smR free for sred overlay

  // ---- phase D: attention (scores + softmax + ctx) from LDS pots ----
  float* sred = (float*)smR;            // 8*256 f32
  float* wbuf = (float*)(smR + 8192);   // 64 f32
  const int m = lane & 15;
  const int quad = lane >> 4;
  const int koff = quad * 8;

  v4f a0 = {0.f, 0.f, 0.f, 0.f}, a1 = {0.f, 0.f, 0.f, 0.f};
  {
    const int axor = (m & 7) << 3;      // row 15 zeroed -> deterministic
    const int abase = m * 2048 + koff;
    const unsigned short* B0p = w1t + (size_t)m * 2048 + koff;
    const unsigned short* B1p = w1t + (size_t)(m + 16) * 2048 + koff;
#pragma unroll
    for (int c = wv * 8; c < wv * 8 + 8; ++c) {
      v8h A = *(const v8h*)(pots_s + ((abase + c * 32) ^ axor));
      v8h B0 = *(const v8h*)(B0p + c * 32);
      v8h B1 = *(const v8h*)(B1p + c * 32);
      a0 = __builtin_amdgcn_mfma_f32_16x16x32_f16(A, B0, a0, 0, 0, 0);
      a1 = __builtin_amdgcn_mfma_f32_16x16x32_f16(A, B1, a1, 0, 0, 0);
    }
  }
  // 2-stage cross-wave reduction of the 8 per-wave partials
  if (wv >= 4) {
#pragma unroll
    for (int j = 0; j < 4; ++j) {
      sred[j * 256 + (wv - 4) * 64 + lane] = a0[j];
      sred[(j + 4) * 256 + (wv - 4) * 64 + lane] = a1[j];
    }
  }
  __syncthreads();
  if (wv < 4) {
#pragma unroll
    for (int j = 0; j < 4; ++j) {
      a0[j] += sred[j * 256 + wv * 64 + lane];
      a1[j] += sred[(j + 4) * 256 + wv * 64 + lane];
      sred[j * 256 + wv * 64 + lane] = a0[j];      // same addr this thread read
      sred[(j + 4) * 256 + wv * 64 + lane] = a1[j];
    }
  }
  __syncthreads();
  if (tid < 256) {
    float s0[4], s1[4];
#pragma unroll
    for (int j = 0; j < 4; ++j) {
      s0[j] = sred[j * 256 + 0 * 64 + lane] + sred[j * 256 + 1 * 64 + lane]
            + sred[j * 256 + 2 * 64 + lane] + sred[j * 256 + 3 * 64 + lane];
      s1[j] = sred[(j + 4) * 256 + 0 * 64 + lane] + sred[(j + 4) * 256 + 1 * 64 + lane]
            + sred[(j + 4) * 256 + 2 * 64 + lane] + sred[(j + 4) * 256 + 3 * 64 + lane];
    }
    float wlar[16];
    {
      const int n = m;
      const float b1a = attn_b1[n], b1b = attn_b1[n + 16];
      const float w2a = attn_w2[n], w2b = attn_w2[n + 16];
      const float b2 = attn_b2[0];
      float sc[4];
#pragma unroll
      for (int r = 0; r < 4; ++r) {
        float v = tanhf(s0[r] + b1a) * w2a + tanhf(s1[r] + b1b) * w2b;
        v += __shfl_xor(v, 1, 64);
        v += __shfl_xor(v, 2, 64);
        v += __shfl_xor(v, 4, 64);
        v += __shfl_xor(v, 8, 64);
        sc[r] = v + b2;
      }
      float mx = -1e30f;
#pragma unroll
      for (int r = 0; r < 4; ++r) if (quad * 4 + r < 15) mx = fmaxf(mx, sc[r]);
      mx = fmaxf(mx, __shfl_xor(mx, 16, 64));
      mx = fmaxf(mx, __shfl_xor(mx, 32, 64));
      float e[4], den = 0.f;
#pragma unroll
      for (int r = 0; r < 4; ++r) {
        e[r] = (quad * 4 + r < 15) ? expf(sc[r] - mx) : 0.f;
        den += e[r];
      }
      den += __shfl_xor(den, 16, 64);
      den += __shfl_xor(den, 32, 64);
      const float inv = 1.f / den;
      if ((lane & 15) == 0) {
        v4f wq = {e[0] * inv, e[1] * inv, e[2] * inv, e[3] * inv};
        *(v4f*)&wbuf[wv * 16 + quad * 4] = wq;
      }
      // same-wave LDS RAW: ordered by lgkmcnt, no barrier needed
#pragma unroll
      for (int q4 = 0; q4 < 4; ++q4) {
        float4 v = *(const float4*)&wbuf[wv * 16 + q4 * 4];
        wlar[q4 * 4 + 0] = v.x; wlar[q4 * 4 + 1] = v.y;
        wlar[q4 * 4 + 2] = v.z; wlar[q4 * 4 + 3] = v.w;
      }
    }
    // ctx = sum_t w_t * pots[t] (swizzled LDS rows, conflict-free)
    float cv[8] = {0.f, 0.f, 0.f, 0.f, 0.f, 0.f, 0.f, 0.f};
#pragma unroll
    for (int t = 0; t < 15; ++t) {
      const int idx = (t * 2048 + tid * 8) ^ ((t & 7) << 3);
      v8h pv = *(const v8h*)(pots_s + idx);
      const float w = wlar[t];
#pragma unroll
      for (int j = 0; j < 8; ++j) cv[j] = fmaf(w, (float)pv[j], cv[j]);
    }
    unsigned short hv[8], lv[8];
#pragma unroll
    for (int j = 0; j < 8; ++j) {
      unsigned short h = bf16t(cv[j]);
      hv[j] = h;
      lv[j] = bf16t(cv[j] - bf16tof(h));
    }
    *(uint4*)(ctxh + (size_t)blockIdx.x * 2048 + tid * 8) = *(const uint4*)hv;
    *(uint4*)(ctxl + (size_t)blockIdx.x * 2048 + tid * 8) = *(const uint4*)lv;
  }
}

// ================= K4: classifier, MFMA bf16 hi/lo =================
__global__ __launch_bounds__(256) void k_cls(
    const unsigned short* __restrict__ ctxh, const unsigned short* __restrict__ ctxl,
    const unsigned short* __restrict__ cw1h, const unsigned short* __restrict__ cw1l,
    const float* __restrict__ cls_b1,
    const float* __restrict__ ln_g, const float* __restrict__ ln_b,
    const float* __restrict__ cls_w2, const float* __restrict__ cls_b2,
    float* __restrict__ out, int b0)
{
  __shared__ float hbuf[16 * 132];
  const int tid = threadIdx.x;
  const int lane = tid & 63;
  const int wv = tid >> 6;
  const int m = lane & 15;
  const int quad = lane >> 4;
  const int koff = quad * 8;
  const int r0l = blockIdx.x * 16;

  v4f a0 = {0.f, 0.f, 0.f, 0.f}, a1 = {0.f, 0.f, 0.f, 0.f};
  {
    const unsigned short* Ah = ctxh + (size_t)(r0l + m) * 2048;
    const unsigned short* Al = ctxl + (size_t)(r0l + m) * 2048;
    const int n0 = wv * 32 + m;
    const unsigned short* B0h = cw1h + (size_t)n0 * 2048;
    const unsigned short* B0l = cw1l + (size_t)n0 * 2048;
    const unsigned short* B1h = cw1h + (size_t)(n0 + 16) * 2048;
    const unsigned short* B1l = cw1l + (size_t)(n0 + 16) * 2048;
#pragma unroll 4
    for (int kc = 0; kc < 64; ++kc) {
      const int kb = kc * 32 + koff;
      v8s vAh = *(const v8s*)(Ah + kb);
      v8s vAl = *(const v8s*)(Al + kb);
      v8s vB0h = *(const v8s*)(B0h + kb);
      v8s vB0l = *(const v8s*)(B0l + kb);
      v8s vB1h = *(const v8s*)(B1h + kb);
      v8s vB1l = *(const v8s*)(B1l + kb);
      a0 = __builtin_amdgcn_mfma_f32_16x16x32_bf16(vAh, vB0h, a0, 0, 0, 0);
      a0 = __builtin_amdgcn_mfma_f32_16x16x32_bf16(vAl, vB0h, a0, 0, 0, 0);
      a0 = __builtin_amdgcn_mfma_f32_16x16x32_bf16(vAh, vB0l, a0, 0, 0, 0);
      a1 = __builtin_amdgcn_mfma_f32_16x16x32_bf16(vAh, vB1h, a1, 0, 0, 0);
      a1 = __builtin_amdgcn_mfma_f32_16x16x32_bf16(vAl, vB1h, a1, 0, 0, 0);
      a1 = __builtin_amdgcn_mfma_f32_16x16x32_bf16(vAh, vB1l, a1, 0, 0, 0);
    }
  }
  {
    const int n0 = wv * 32 + m;
    const float bb0 = cls_b1[n0], bb1 = cls_b1[n0 + 16];
#pragma unroll
    for (int r = 0; r < 4; ++r) {
      const int row = quad * 4 + r;
      hbuf[row * 132 + n0] = a0[r] + bb0;
      hbuf[row * 132 + n0 + 16] = a1[r] + bb1;
    }
  }
  __syncthreads();
  const float g0c = ln_g[lane], g1c = ln_g[lane + 64];
  const float b0c = ln_b[lane], b1c = ln_b[lane + 64];
  const float4 w2a = *(const float4*)(cls_w2 + lane * 4);
  const float4 w2b = *(const float4*)(cls_w2 + (lane + 64) * 4);
#pragma unroll
  for (int rr = 0; rr < 4; ++rr) {
    const int r = wv * 4 + rr;
    const float x0 = hbuf[r * 132 + lane];
    const float x1 = hbuf[r * 132 + 64 + lane];
    float s = x0 + x1, sq = x0 * x0 + x1 * x1;
#pragma unroll
    for (int mm = 32; mm >= 1; mm >>= 1) {
      s += __shfl_xor(s, mm, 64);
      sq += __shfl_xor(sq, mm, 64);
    }
    const float mu = s * (1.f / 128.f);
    const float var = sq * (1.f / 128.f) - mu * mu;
    const float rstd = rsqrtf(var + 1e-5f);
    float h0 = (x0 - mu) * rstd * g0c + b0c;
    float h1 = (x1 - mu) * rstd * g1c + b1c;
    h0 = 0.5f * h0 * (1.f + erff(h0 * 0.7071067811865475f));
    h1 = 0.5f * h1 * (1.f + erff(h1 * 0.7071067811865475f));
    float o0 = h0 * w2a.x + h1 * w2b.x;
    float o1 = h0 * w2a.y + h1 * w2b.y;
    float o2 = h0 * w2a.z + h1 * w2b.z;
    float o3 = h0 * w2a.w + h1 * w2b.w;
#pragma unroll
    for (int mm = 32; mm >= 1; mm >>= 1) {
      o0 += __shfl_xor(o0, mm, 64);
      o1 += __shfl_xor(o1, mm, 64);
      o2 += __shfl_xor(o2, mm, 64);
      o3 += __shfl_xor(o3, mm, 64);
    }
    if (lane == 0) {
      *(float4*)(out + (size_t)(b0 + r0l + r) * 4) =
          make_float4(o0 + cls_b2[0], o1 + cls_b2[1], o2 + cls_b2[2], o3 + cls_b2[3]);
    }
  }
}

// ================= host =================
extern "C" void kernel_launch(void* const* d_in, const int* in_sizes, int n_in,
                              void* d_out, int out_size, void* d_ws, size_t ws_size,
                              hipStream_t stream) {
  const float* L_norm   = (const float*)d_in[0];
  const float* X_seq    = (const float*)d_in[1];
  const float* conv_w   = (const float*)d_in[2];
  const float* conv_b   = (const float*)d_in[3];
  const float* bn_gamma = (const float*)d_in[4];
  const float* bn_beta  = (const float*)d_in[5];
  const float* bn_mean  = (const float*)d_in[6];
  const float* bn_var   = (const float*)d_in[7];
  const float* gcn1_w   = (const float*)d_in[8];
  const float* gcn1_b   = (const float*)d_in[9];
  const float* mask1    = (const float*)d_in[10];
  const float* gcn2_w   = (const float*)d_in[11];
  const float* gcn2_b   = (const float*)d_in[12];
  const float* mask2    = (const float*)d_in[13];
  const float* beta2    = (const float*)d_in[14];
  const float* attn_w1  = (const float*)d_in[15];
  const float* attn_b1  = (const float*)d_in[16];
  const float* attn_w2  = (const float*)d_in[17];
  const float* attn_b2  = (const float*)d_in[18];
  const float* cls_w1   = (const float*)d_in[19];
  const float* cls_b1   = (const float*)d_in[20];
  const float* ln_gamma = (const float*)d_in[21];
  const float* ln_beta  = (const float*)d_in[22];
  const float* cls_w2   = (const float*)d_in[23];
  const float* cls_b2   = (const float*)d_in[24];

  char* ws = (char*)d_ws;
  float* wsf = (float*)d_ws;
  unsigned short* w1t  = (unsigned short*)(ws + OFF_W1T);
  unsigned short* cw1h = (unsigned short*)(ws + OFF_CW1H);
  unsigned short* cw1l = (unsigned short*)(ws + OFF_CW1L);

  // ctx hi/lo planes (8192 B per batch); equalize chunks to avoid tail round
  long long avail = (long long)ws_size - (long long)OFF_CTX;
  int chunk = 4096;
  if (avail < 8192LL * 4096LL) {
    long long cmax = (avail > 0) ? (avail / 8192) : 64;
    if (cmax > 4096) cmax = 4096;
    cmax &= ~63LL;
    if (cmax < 64) cmax = 64;
    int nch = (int)((4096 + cmax - 1) / cmax);
    long long ceq = ((4096 / nch) + 63) & ~63LL;
    while (ceq * nch < 4096) ceq += 64;
    if (ceq > cmax) ceq = cmax;
    chunk = (int)ceq;
  }
  unsigned short* ctxh = (unsigned short*)(ws + OFF_CTX);
  unsigned short* ctxl = ctxh + (size_t)chunk * 2048;

  hipLaunchKernelGGL(k_prep, dim3(256), dim3(256), 0, stream,
                     mask1, mask2, conv_w, conv_b, bn_gamma, bn_beta, bn_mean, bn_var,
                     attn_w1, cls_w1, wsf, w1t, cw1h, cw1l);

  for (int b0 = 0; b0 < 4096; b0 += chunk) {
    int cur = 4096 - b0;
    if (cur > chunk) cur = chunk;
    hipLaunchKernelGGL(k_fused, dim3(cur), dim3(512), 0, stream,
                       L_norm, X_seq, gcn1_w, gcn1_b, gcn2_w, gcn2_b, beta2,
                       wsf, w1t, attn_b1, attn_w2, attn_b2, ctxh, ctxl, b0);
    hipLaunchKernelGGL(k_cls, dim3(cur / 16), dim3(256), 0, stream,
                       ctxh, ctxl, cw1h, cw1l, cls_b1, ln_gamma, ln_beta, cls_w2, cls_b2,
                       (float*)d_out, b0);
  }
}

// Round 5
// 517.542 us; speedup vs baseline: 1.2965x; 1.2965x over previous
//
#include <hip/hip_runtime.h>
#include <math.h>

// ---------------- workspace layout (bytes unless _F) ----------------
#define WS_M1_F    0           // 4096 f32
#define WS_M2_F    4096        // 4096 f32
#define WS_BNSC_F  8192        // 64 f32
#define WS_BNSH_F  8256        // 64 f32
#define WS_WT_F    8448        // 12288 f32 (conv_w transposed [ik][o])
#define OFF_W1T    83968       // u16[32*2048]  attn_w1^T fp16  -> +131072 = 215040
#define OFF_CW1H   215040      // u16[128*2048] cls_w1^T bf16-hi -> +524288 = 739328
#define OFF_CW1L   739328      // u16[128*2048] cls_w1^T bf16-lo -> +524288 = 1263616
#define OFF_CTX    1263616     // per-chunk ctx hi/lo planes (8192 B/batch)

typedef _Float16 v8h __attribute__((ext_vector_type(8)));
typedef short v8s __attribute__((ext_vector_type(8)));
typedef float v4f __attribute__((ext_vector_type(4)));
typedef float v16f __attribute__((ext_vector_type(16)));

__device__ __forceinline__ unsigned short f2h_u(float x) {
  _Float16 h = (_Float16)x;
  union { _Float16 h; unsigned short u; } v; v.h = h; return v.u;
}
__device__ __forceinline__ unsigned short bf16t(float x) {
  union { float f; unsigned int u; } v; v.f = x; return (unsigned short)(v.u >> 16);
}
__device__ __forceinline__ float bf16tof(unsigned short s) {
  union { unsigned int u; float f; } v; v.u = ((unsigned int)s) << 16; return v.f;
}

// ================= K1: prep (multi-block) =================
__global__ __launch_bounds__(256) void k_prep(
    const float* __restrict__ mask1, const float* __restrict__ mask2,
    const float* __restrict__ conv_w, const float* __restrict__ conv_b,
    const float* __restrict__ bn_gamma, const float* __restrict__ bn_beta,
    const float* __restrict__ bn_mean, const float* __restrict__ bn_var,
    const float* __restrict__ attn_w1, const float* __restrict__ cls_w1,
    float* __restrict__ wsf, unsigned short* __restrict__ w1t,
    unsigned short* __restrict__ cw1h, unsigned short* __restrict__ cw1l)
{
  const int gid = blockIdx.x * 256 + threadIdx.x;
  const int gsz = gridDim.x * 256;
  float* m1 = wsf + WS_M1_F;
  float* m2 = wsf + WS_M2_F;
  float* bnsc = wsf + WS_BNSC_F;
  float* bnsh = wsf + WS_BNSH_F;
  float* wT = wsf + WS_WT_F;
  for (int e = gid; e < 4096; e += gsz) {
    int i = e >> 6, j = e & 63;
    float s1 = mask1[e] + mask1[j * 64 + i];
    float s2 = mask2[e] + mask2[j * 64 + i];
    m1[e] = 0.5f / (1.f + expf(-s1));
    m2[e] = 0.5f / (1.f + expf(-s2));
  }
  for (int e = gid; e < 64; e += gsz) {
    float sc = bn_gamma[e] * rsqrtf(bn_var[e] + 1e-5f);
    bnsc[e] = sc;
    bnsh[e] = (conv_b[e] - bn_mean[e]) * sc + bn_beta[e];
  }
  for (int e = gid; e < 12288; e += gsz) {
    int o = e / 192, ik = e % 192;
    wT[ik * 64 + o] = conv_w[e];
  }
  // attn_w1^T: read coalesced, write scattered
  for (int f = gid; f < 65536; f += gsz) {
    int i = f >> 5, n = f & 31;
    w1t[n * 2048 + i] = f2h_u(attn_w1[f]);
  }
  // cls_w1^T hi/lo: read coalesced, write scattered
  for (int f = gid; f < 262144; f += gsz) {
    int k = f >> 7, n = f & 127;
    float x = cls_w1[f];
    unsigned short h = bf16t(x);
    cw1h[n * 2048 + k] = h;
    cw1l[n * 2048 + k] = bf16t(x - bf16tof(h));
  }
}

// ===== K2: fused conv+BN -> recurrence -> attention, one block per batch =====
// 256 threads (4 waves). LDS: pots_s 65536 B + smR 11776 B = 77312 B
// -> 2 blocks/CU, cross-block phase overlap (proven round 3).
// Phase C: 2 barriers/step. gcn1 is computed REDUNDANTLY by every MFMA thread
// for exactly the 16 (channel,node) states its B-fragment needs: removes the
// middle barrier and the spk1T LDS round-trip. Arithmetic is bit-identical.
__global__ __launch_bounds__(256) void k_fused(
    const float* __restrict__ L_norm, const float* __restrict__ X_seq,
    const float* __restrict__ gcn1_w, const float* __restrict__ gcn1_b,
    const float* __restrict__ gcn2_w, const float* __restrict__ gcn2_b,
    const float* __restrict__ beta2p, const float* __restrict__ wsf,
    const unsigned short* __restrict__ w1t,
    const float* __restrict__ attn_b1, const float* __restrict__ attn_w2,
    const float* __restrict__ attn_b2,
    unsigned short* __restrict__ ctxh, unsigned short* __restrict__ ctxl,
    int b0)
{
  __shared__ __align__(16) unsigned short pots_s[16 * 2048];
  __shared__ __align__(16) char smR[11776];
  float* xcur = (float*)smR;                          // 960 f32   [0,3840)
  float* zp = (float*)(smR + 3840);                   // 128 f32   [3840,4352)
  float* Z2f = (float*)(smR + 6656);                  // 64*20 f32 [6656,11776)

  const int tid = threadIdx.x;
  const int lane = tid & 63;
  const int wv = tid >> 6;
  const int b = b0 + blockIdx.x;

  const float* m1 = wsf + WS_M1_F;
  const float* m2 = wsf + WS_M2_F;

  // ---- phase A: conv + BN (xraw staged in pots_s area, dead until t=1) ----
  {
    float* xraw = (float*)pots_s;
    for (int e = tid; e < 960; e += 256) xraw[e] = X_seq[(size_t)b * 960 + e];
    // zero pots_s row 15 (feeds the discarded t=15 MFMA A-row): determinism
    *(uint4*)&pots_s[15 * 2048 + tid * 8] = make_uint4(0u, 0u, 0u, 0u);
    __syncthreads();
    const float* bnsc = wsf + WS_BNSC_F;
    const float* bnsh = wsf + WS_BNSH_F;
    const float* wT = wsf + WS_WT_F;
    const int o = lane;
    const int t0 = wv, t1 = wv + 4, t2 = wv + 8, t3 = wv + 12;
    float a0 = 0.f, a1 = 0.f, a2 = 0.f, a3 = 0.f;
    for (int i = 0; i < 64; ++i) {
      const float w0 = wT[(3 * i + 0) * 64 + o];
      const float w1 = wT[(3 * i + 1) * 64 + o];
      const float w2 = wT[(3 * i + 2) * 64 + o];
      float xa = (t0 >= 2) ? xraw[(t0 - 2) * 64 + i] : 0.f;
      float xb = (t0 >= 1) ? xraw[(t0 - 1) * 64 + i] : 0.f;
      a0 += w0 * xa + w1 * xb + w2 * xraw[t0 * 64 + i];
      a1 += w0 * xraw[(t1 - 2) * 64 + i] + w1 * xraw[(t1 - 1) * 64 + i] + w2 * xraw[t1 * 64 + i];
      a2 += w0 * xraw[(t2 - 2) * 64 + i] + w1 * xraw[(t2 - 1) * 64 + i] + w2 * xraw[t2 * 64 + i];
      if (t3 < 15)
        a3 += w0 * xraw[(t3 - 2) * 64 + i] + w1 * xraw[(t3 - 1) * 64 + i] + w2 * xraw[t3 * 64 + i];
    }
    const float sc = bnsc[o], sh = bnsh[o];
    xcur[t0 * 64 + o] = a0 * sc + sh;
    xcur[t1 * 64 + o] = a1 * sc + sh;
    xcur[t2 * 64 + o] = a2 * sc + sh;
    if (t3 < 15) xcur[t3 * 64 + o] = a3 * sc + sh;
    __syncthreads();
  }

  // ---- phase B: register prep ----
  float L1h[32];
  const int kb1 = (wv & 1) * 32;
  if (wv >= 2) {
    const float* Lb = L_norm + (size_t)b * 4096 + lane * 64 + kb1;
    const float* mr = m1 + lane * 64 + kb1;
#pragma unroll
    for (int q4 = 0; q4 < 8; ++q4) {
      float4 lv = *(const float4*)(Lb + 4 * q4);
      float4 mv = *(const float4*)(mr + 4 * q4);
      L1h[4 * q4 + 0] = lv.x * mv.x;
      L1h[4 * q4 + 1] = lv.y * mv.y;
      L1h[4 * q4 + 2] = lv.z * mv.z;
      L1h[4 * q4 + 3] = lv.w * mv.w;
    }
  }

  v8s A_hi[2], A_lo[2];
  {
    const int irow = wv * 16 + (lane & 15);
    const int quad = (lane >> 4) & 3;
#pragma unroll
    for (int kb = 0; kb < 2; ++kb) {
      const float* Lb = L_norm + (size_t)b * 4096 + irow * 64 + kb * 32 + quad * 8;
      const float* mr = m2 + irow * 64 + kb * 32 + quad * 8;
      float4 la = *(const float4*)Lb, lb2 = *(const float4*)(Lb + 4);
      float4 ma = *(const float4*)mr, mb = *(const float4*)(mr + 4);
      float v[8] = { la.x * ma.x, la.y * ma.y, la.z * ma.z, la.w * ma.w,
                     lb2.x * mb.x, lb2.y * mb.y, lb2.z * mb.z, lb2.w * mb.w };
#pragma unroll
      for (int e = 0; e < 8; ++e) {
        unsigned short h = bf16t(v[e]);
        unsigned short l = bf16t(v[e] - bf16tof(h));
        A_hi[kb][e] = (short)h;
        A_lo[kb][e] = (short)l;
      }
    }
  }

  v8s W_hi, W_lo;
  {
    const int n = lane & 31;
    const int kh = (lane >> 5) & 1;
#pragma unroll
    for (int e = 0; e < 8; ++e) {
      float x = gcn2_w[(kh * 8 + e) * 32 + n];
      unsigned short h = bf16t(x);
      unsigned short l = bf16t(x - bf16tof(h));
      W_hi[e] = (short)h;
      W_lo[e] = (short)l;
    }
  }

  const float b2h = gcn2_b[lane & 31];
  const float beta2 = beta2p[0];

  // per-thread gcn1 constants and replicated state (c16 = channel, 16 nodes)
  const int c16 = lane & 15;
  const int quad = (lane >> 4) & 3;
  const int qa = quad * 8;
  const float wcc = gcn1_w[c16];
  const float bcc = gcn1_b[c16];
  float mgA[8], mgB[8];
#pragma unroll
  for (int e = 0; e < 8; ++e) { mgA[e] = 0.f; mgB[e] = 0.f; }

  float mem_t = 0.f;
  v16f mg2;
#pragma unroll
  for (int r = 0; r < 16; ++r) mg2[r] = 0.f;

  auto stage_b = [&](int tm1) {
    const int m = lane & 31;
    const int half = lane >> 5;
    const float* zr = Z2f + (wv * 32 + m) * 20 + half * 8;
    float4 za = *(const float4*)zr;
    float4 zb = *(const float4*)(zr + 4);
    float vv[8] = {za.x, za.y, za.z, za.w, zb.x, zb.y, zb.z, zb.w};
    v8s Ah, Al;
#pragma unroll
    for (int e = 0; e < 8; ++e) {
      unsigned short h = bf16t(vv[e]);
      unsigned short l = bf16t(vv[e] - bf16tof(h));
      Ah[e] = (short)h;
      Al[e] = (short)l;
    }
    v16f acc;
#pragma unroll
    for (int r = 0; r < 16; ++r) {
      float rs = (mg2[r] > 1.f) ? 1.f : 0.f;
      acc[r] = fmaf(beta2, mg2[r], b2h - rs);
    }
    acc = __builtin_amdgcn_mfma_f32_32x32x16_bf16(Ah, W_hi, acc, 0, 0, 0);
    acc = __builtin_amdgcn_mfma_f32_32x32x16_bf16(Al, W_hi, acc, 0, 0, 0);
    acc = __builtin_amdgcn_mfma_f32_32x32x16_bf16(Ah, W_lo, acc, 0, 0, 0);
    mg2 = acc;
    const int xorv = (tm1 & 7) << 3;
    const int base = tm1 * 2048 + m;
#pragma unroll
    for (int r = 0; r < 16; ++r) {
      int i = wv * 32 + (r & 3) + 8 * (r >> 2) + 4 * half;
      pots_s[(base + i * 32) ^ xorv] = f2h_u(acc[r]);
    }
  };

  // ---- phase C: 15-step recurrence, 2 barriers per step ----
  for (int t = 0; t < 15; ++t) {
    if (wv >= 2) {
      float xc = xcur[t * 64 + lane];
      float rs = (mem_t > 1.f) ? 1.f : 0.f;
      mem_t = 0.9f * mem_t + xc - rs;
      float sp = (mem_t > 1.f) ? 1.f : 0.f;
      int spi = __float_as_int(sp);
      float zh = 0.f;
#pragma unroll
      for (int k = 0; k < 32; ++k) {
        float s = __int_as_float(__builtin_amdgcn_readlane(spi, kb1 + k));
        zh = fmaf(s, L1h[k], zh);
      }
      zp[(wv & 1) * 64 + lane] = zh;
    } else if (t > 0) {
      stage_b(t - 1);
    }
    __syncthreads();
    {
      // z[node] = zp[node] + zp[64+node]; this thread needs nodes
      // {qa..qa+7} (B0, k-block 0) and {32+qa..32+qa+7} (B1, k-block 1).
      float4 pa0 = *(const float4*)&zp[qa];
      float4 pa1 = *(const float4*)&zp[qa + 4];
      float4 pa2 = *(const float4*)&zp[64 + qa];
      float4 pa3 = *(const float4*)&zp[68 + qa];
      float4 pb0 = *(const float4*)&zp[32 + qa];
      float4 pb1 = *(const float4*)&zp[36 + qa];
      float4 pb2 = *(const float4*)&zp[96 + qa];
      float4 pb3 = *(const float4*)&zp[100 + qa];
      float zA[8] = {pa0.x + pa2.x, pa0.y + pa2.y, pa0.z + pa2.z, pa0.w + pa2.w,
                     pa1.x + pa3.x, pa1.y + pa3.y, pa1.z + pa3.z, pa1.w + pa3.w};
      float zB[8] = {pb0.x + pb2.x, pb0.y + pb2.y, pb0.z + pb2.z, pb0.w + pb2.w,
                     pb1.x + pb3.x, pb1.y + pb3.y, pb1.z + pb3.z, pb1.w + pb3.w};
      v8s B0, B1;
#pragma unroll
      for (int e = 0; e < 8; ++e) {
        float curA = fmaf(zA[e], wcc, bcc);
        float rsA = (mgA[e] > 1.f) ? 1.f : 0.f;
        mgA[e] = 0.85f * mgA[e] + curA - rsA;
        B0[e] = (mgA[e] > 1.f) ? (short)0x3F80 : (short)0;
        float curB = fmaf(zB[e], wcc, bcc);
        float rsB = (mgB[e] > 1.f) ? 1.f : 0.f;
        mgB[e] = 0.85f * mgB[e] + curB - rsB;
        B1[e] = (mgB[e] > 1.f) ? (short)0x3F80 : (short)0;
      }
      v4f acc = {0.f, 0.f, 0.f, 0.f};
      acc = __builtin_amdgcn_mfma_f32_16x16x32_bf16(A_hi[0], B0, acc, 0, 0, 0);
      acc = __builtin_amdgcn_mfma_f32_16x16x32_bf16(A_lo[0], B0, acc, 0, 0, 0);
      acc = __builtin_amdgcn_mfma_f32_16x16x32_bf16(A_hi[1], B1, acc, 0, 0, 0);
      acc = __builtin_amdgcn_mfma_f32_16x16x32_bf16(A_lo[1], B1, acc, 0, 0, 0);
      const int r0 = wv * 16 + quad * 4;
#pragma unroll
      for (int r = 0; r < 4; ++r) Z2f[(r0 + r) * 20 + c16] = acc[r];
    }
    __syncthreads();
  }
  if (wv < 2) stage_b(14);
  __syncthreads();   // pots_s complete; smR free for sred overlay

  // ---- phase D: attention (scores + softmax + ctx) from LDS pots ----
  float* sred = (float*)smR;            // 8*256 f32
  float* wbuf = (float*)(smR + 8192);   // 64 f32
  const int m = lane & 15;
  const int koff = quad * 8;

  v4f a0 = {0.f, 0.f, 0.f, 0.f}, a1 = {0.f, 0.f, 0.f, 0.f};
  {
    const int axor = (m & 7) << 3;      // row 15 zeroed -> deterministic
    const int abase = m * 2048 + koff;
    const unsigned short* B0p = w1t + (size_t)m * 2048 + koff;
    const unsigned short* B1p = w1t + (size_t)(m + 16) * 2048 + koff;
#pragma unroll 4
    for (int c = wv * 16; c < wv * 16 + 16; ++c) {
      v8h A = *(const v8h*)(pots_s + ((abase + c * 32) ^ axor));
      v8h B0 = *(const v8h*)(B0p + c * 32);
      v8h B1 = *(const v8h*)(B1p + c * 32);
      a0 = __builtin_amdgcn_mfma_f32_16x16x32_f16(A, B0, a0, 0, 0, 0);
      a1 = __builtin_amdgcn_mfma_f32_16x16x32_f16(A, B1, a1, 0, 0, 0);
    }
  }
#pragma unroll
  for (int j = 0; j < 4; ++j) {
    sred[j * 256 + tid] = a0[j];
    sred[(j + 4) * 256 + tid] = a1[j];
  }
  __syncthreads();
  float s0[4], s1[4];
#pragma unroll
  for (int j = 0; j < 4; ++j) {
    s0[j] = sred[j * 256 + 0 * 64 + lane] + sred[j * 256 + 1 * 64 + lane]
          + sred[j * 256 + 2 * 64 + lane] + sred[j * 256 + 3 * 64 + lane];
    s1[j] = sred[(j + 4) * 256 + 0 * 64 + lane] + sred[(j + 4) * 256 + 1 * 64 + lane]
          + sred[(j + 4) * 256 + 2 * 64 + lane] + sred[(j + 4) * 256 + 3 * 64 + lane];
  }
  float wlar[16];
  {
    const int n = m;
    const float b1a = attn_b1[n], b1b = attn_b1[n + 16];
    const float w2a = attn_w2[n], w2b = attn_w2[n + 16];
    const float b2 = attn_b2[0];
    float sc[4];
#pragma unroll
    for (int r = 0; r < 4; ++r) {
      float v = tanhf(s0[r] + b1a) * w2a + tanhf(s1[r] + b1b) * w2b;
      v += __shfl_xor(v, 1, 64);
      v += __shfl_xor(v, 2, 64);
      v += __shfl_xor(v, 4, 64);
      v += __shfl_xor(v, 8, 64);
      sc[r] = v + b2;
    }
    float mx = -1e30f;
#pragma unroll
    for (int r = 0; r < 4; ++r) if (quad * 4 + r < 15) mx = fmaxf(mx, sc[r]);
    mx = fmaxf(mx, __shfl_xor(mx, 16, 64));
    mx = fmaxf(mx, __shfl_xor(mx, 32, 64));
    float e[4], den = 0.f;
#pragma unroll
    for (int r = 0; r < 4; ++r) {
      e[r] = (quad * 4 + r < 15) ? expf(sc[r] - mx) : 0.f;
      den += e[r];
    }
    den += __shfl_xor(den, 16, 64);
    den += __shfl_xor(den, 32, 64);
    const float inv = 1.f / den;
    if ((lane & 15) == 0) {
      v4f wq = {e[0] * inv, e[1] * inv, e[2] * inv, e[3] * inv};
      *(v4f*)&wbuf[wv * 16 + quad * 4] = wq;
    }
    // same-wave LDS RAW: ordered by lgkmcnt, no barrier needed
#pragma unroll
    for (int q4 = 0; q4 < 4; ++q4) {
      float4 v = *(const float4*)&wbuf[wv * 16 + q4 * 4];
      wlar[q4 * 4 + 0] = v.x; wlar[q4 * 4 + 1] = v.y;
      wlar[q4 * 4 + 2] = v.z; wlar[q4 * 4 + 3] = v.w;
    }
  }
  // ctx = sum_t w_t * pots[t] (swizzled LDS rows, conflict-free)
  float cv[8] = {0.f, 0.f, 0.f, 0.f, 0.f, 0.f, 0.f, 0.f};
#pragma unroll
  for (int t = 0; t < 15; ++t) {
    const int idx = (t * 2048 + tid * 8) ^ ((t & 7) << 3);
    v8h pv = *(const v8h*)(pots_s + idx);
    const float w = wlar[t];
#pragma unroll
    for (int j = 0; j < 8; ++j) cv[j] = fmaf(w, (float)pv[j], cv[j]);
  }
  unsigned short hv[8], lv[8];
#pragma unroll
  for (int j = 0; j < 8; ++j) {
    unsigned short h = bf16t(cv[j]);
    hv[j] = h;
    lv[j] = bf16t(cv[j] - bf16tof(h));
  }
  *(uint4*)(ctxh + (size_t)blockIdx.x * 2048 + tid * 8) = *(const uint4*)hv;
  *(uint4*)(ctxl + (size_t)blockIdx.x * 2048 + tid * 8) = *(const uint4*)lv;
}

// ================= K4: classifier, MFMA bf16 hi/lo =================
__global__ __launch_bounds__(256) void k_cls(
    const unsigned short* __restrict__ ctxh, const unsigned short* __restrict__ ctxl,
    const unsigned short* __restrict__ cw1h, const unsigned short* __restrict__ cw1l,
    const float* __restrict__ cls_b1,
    const float* __restrict__ ln_g, const float* __restrict__ ln_b,
    const float* __restrict__ cls_w2, const float* __restrict__ cls_b2,
    float* __restrict__ out, int b0)
{
  __shared__ float hbuf[16 * 132];
  const int tid = threadIdx.x;
  const int lane = tid & 63;
  const int wv = tid >> 6;
  const int m = lane & 15;
  const int quad = lane >> 4;
  const int koff = quad * 8;
  const int r0l = blockIdx.x * 16;

  v4f a0 = {0.f, 0.f, 0.f, 0.f}, a1 = {0.f, 0.f, 0.f, 0.f};
  {
    const unsigned short* Ah = ctxh + (size_t)(r0l + m) * 2048;
    const unsigned short* Al = ctxl + (size_t)(r0l + m) * 2048;
    const int n0 = wv * 32 + m;
    const unsigned short* B0h = cw1h + (size_t)n0 * 2048;
    const unsigned short* B0l = cw1l + (size_t)n0 * 2048;
    const unsigned short* B1h = cw1h + (size_t)(n0 + 16) * 2048;
    const unsigned short* B1l = cw1l + (size_t)(n0 + 16) * 2048;
#pragma unroll 4
    for (int kc = 0; kc < 64; ++kc) {
      const int kb = kc * 32 + koff;
      v8s vAh = *(const v8s*)(Ah + kb);
      v8s vAl = *(const v8s*)(Al + kb);
      v8s vB0h = *(const v8s*)(B0h + kb);
      v8s vB0l = *(const v8s*)(B0l + kb);
      v8s vB1h = *(const v8s*)(B1h + kb);
      v8s vB1l = *(const v8s*)(B1l + kb);
      a0 = __builtin_amdgcn_mfma_f32_16x16x32_bf16(vAh, vB0h, a0, 0, 0, 0);
      a0 = __builtin_amdgcn_mfma_f32_16x16x32_bf16(vAl, vB0h, a0, 0, 0, 0);
      a0 = __builtin_amdgcn_mfma_f32_16x16x32_bf16(vAh, vB0l, a0, 0, 0, 0);
      a1 = __builtin_amdgcn_mfma_f32_16x16x32_bf16(vAh, vB1h, a1, 0, 0, 0);
      a1 = __builtin_amdgcn_mfma_f32_16x16x32_bf16(vAl, vB1h, a1, 0, 0, 0);
      a1 = __builtin_amdgcn_mfma_f32_16x16x32_bf16(vAh, vB1l, a1, 0, 0, 0);
    }
  }
  {
    const int n0 = wv * 32 + m;
    const float bb0 = cls_b1[n0], bb1 = cls_b1[n0 + 16];
#pragma unroll
    for (int r = 0; r < 4; ++r) {
      const int row = quad * 4 + r;
      hbuf[row * 132 + n0] = a0[r] + bb0;
      hbuf[row * 132 + n0 + 16] = a1[r] + bb1;
    }
  }
  __syncthreads();
  const float g0c = ln_g[lane], g1c = ln_g[lane + 64];
  const float b0c = ln_b[lane], b1c = ln_b[lane + 64];
  const float4 w2a = *(const float4*)(cls_w2 + lane * 4);
  const float4 w2b = *(const float4*)(cls_w2 + (lane + 64) * 4);
#pragma unroll
  for (int rr = 0; rr < 4; ++rr) {
    const int r = wv * 4 + rr;
    const float x0 = hbuf[r * 132 + lane];
    const float x1 = hbuf[r * 132 + 64 + lane];
    float s = x0 + x1, sq = x0 * x0 + x1 * x1;
#pragma unroll
    for (int mm = 32; mm >= 1; mm >>= 1) {
      s += __shfl_xor(s, mm, 64);
      sq += __shfl_xor(sq, mm, 64);
    }
    const float mu = s * (1.f / 128.f);
    const float var = sq * (1.f / 128.f) - mu * mu;
    const float rstd = rsqrtf(var + 1e-5f);
    float h0 = (x0 - mu) * rstd * g0c + b0c;
    float h1 = (x1 - mu) * rstd * g1c + b1c;
    h0 = 0.5f * h0 * (1.f + erff(h0 * 0.7071067811865475f));
    h1 = 0.5f * h1 * (1.f + erff(h1 * 0.7071067811865475f));
    float o0 = h0 * w2a.x + h1 * w2b.x;
    float o1 = h0 * w2a.y + h1 * w2b.y;
    float o2 = h0 * w2a.z + h1 * w2b.z;
    float o3 = h0 * w2a.w + h1 * w2b.w;
#pragma unroll
    for (int mm = 32; mm >= 1; mm >>= 1) {
      o0 += __shfl_xor(o0, mm, 64);
      o1 += __shfl_xor(o1, mm, 64);
      o2 += __shfl_xor(o2, mm, 64);
      o3 += __shfl_xor(o3, mm, 64);
    }
    if (lane == 0) {
      *(float4*)(out + (size_t)(b0 + r0l + r) * 4) =
          make_float4(o0 + cls_b2[0], o1 + cls_b2[1], o2 + cls_b2[2], o3 + cls_b2[3]);
    }
  }
}

// ================= host =================
extern "C" void kernel_launch(void* const* d_in, const int* in_sizes, int n_in,
                              void* d_out, int out_size, void* d_ws, size_t ws_size,
                              hipStream_t stream) {
  const float* L_norm   = (const float*)d_in[0];
  const float* X_seq    = (const float*)d_in[1];
  const float* conv_w   = (const float*)d_in[2];
  const float* conv_b   = (const float*)d_in[3];
  const float* bn_gamma = (const float*)d_in[4];
  const float* bn_beta  = (const float*)d_in[5];
  const float* bn_mean  = (const float*)d_in[6];
  const float* bn_var   = (const float*)d_in[7];
  const float* gcn1_w   = (const float*)d_in[8];
  const float* gcn1_b   = (const float*)d_in[9];
  const float* mask1    = (const float*)d_in[10];
  const float* gcn2_w   = (const float*)d_in[11];
  const float* gcn2_b   = (const float*)d_in[12];
  const float* mask2    = (const float*)d_in[13];
  const float* beta2    = (const float*)d_in[14];
  const float* attn_w1  = (const float*)d_in[15];
  const float* attn_b1  = (const float*)d_in[16];
  const float* attn_w2  = (const float*)d_in[17];
  const float* attn_b2  = (const float*)d_in[18];
  const float* cls_w1   = (const float*)d_in[19];
  const float* cls_b1   = (const float*)d_in[20];
  const float* ln_gamma = (const float*)d_in[21];
  const float* ln_beta  = (const float*)d_in[22];
  const float* cls_w2   = (const float*)d_in[23];
  const float* cls_b2   = (const float*)d_in[24];

  char* ws = (char*)d_ws;
  float* wsf = (float*)d_ws;
  unsigned short* w1t  = (unsigned short*)(ws + OFF_W1T);
  unsigned short* cw1h = (unsigned short*)(ws + OFF_CW1H);
  unsigned short* cw1l = (unsigned short*)(ws + OFF_CW1L);

  // ctx hi/lo planes (8192 B per batch); equalize chunks to avoid tail round
  long long avail = (long long)ws_size - (long long)OFF_CTX;
  int chunk = 4096;
  if (avail < 8192LL * 4096LL) {
    long long cmax = (avail > 0) ? (avail / 8192) : 64;
    if (cmax > 4096) cmax = 4096;
    cmax &= ~63LL;
    if (cmax < 64) cmax = 64;
    int nch = (int)((4096 + cmax - 1) / cmax);
    long long ceq = ((4096 / nch) + 63) & ~63LL;
    while (ceq * nch < 4096) ceq += 64;
    if (ceq > cmax) ceq = cmax;
    chunk = (int)ceq;
  }
  unsigned short* ctxh = (unsigned short*)(ws + OFF_CTX);
  unsigned short* ctxl = ctxh + (size_t)chunk * 2048;

  hipLaunchKernelGGL(k_prep, dim3(256), dim3(256), 0, stream,
                     mask1, mask2, conv_w, conv_b, bn_gamma, bn_beta, bn_mean, bn_var,
                     attn_w1, cls_w1, wsf, w1t, cw1h, cw1l);

  for (int b0 = 0; b0 < 4096; b0 += chunk) {
    int cur = 4096 - b0;
    if (cur > chunk) cur = chunk;
    hipLaunchKernelGGL(k_fused, dim3(cur), dim3(256), 0, stream,
                       L_norm, X_seq, gcn1_w, gcn1_b, gcn2_w, gcn2_b, beta2,
                       wsf, w1t, attn_b1, attn_w2, attn_b2, ctxh, ctxl, b0);
    hipLaunchKernelGGL(k_cls, dim3(cur / 16), dim3(256), 0, stream,
                       ctxh, ctxl, cw1h, cw1l, cls_b1, ln_gamma, ln_beta, cls_w2, cls_b2,
                       (float*)d_out, b0);
  }
}

// Round 9
// 501.306 us; speedup vs baseline: 1.3384x; 1.0324x over previous
//
#include <hip/hip_runtime.h>
#include <math.h>

// ---------------- workspace layout (bytes unless _F) ----------------
#define WS_M1_F    0           // 4096 f32
#define WS_M2_F    4096        // 4096 f32
#define WS_BNSC_F  8192        // 64 f32
#define WS_BNSH_F  8256        // 64 f32
#define WS_WT_F    8448        // 12288 f32 (conv_w transposed [ik][o])
#define OFF_W1T    83968       // u16[32*2048]  attn_w1^T fp16  -> +131072 = 215040
#define OFF_CW1H   215040      // u16[128*2048] cls_w1^T bf16-hi -> +524288 = 739328
#define OFF_CW1L   739328      // u16[128*2048] cls_w1^T bf16-lo -> +524288 = 1263616
#define OFF_CTX    1263616     // per-chunk ctx hi/lo planes (8192 B/batch)

typedef _Float16 v8h __attribute__((ext_vector_type(8)));
typedef short v8s __attribute__((ext_vector_type(8)));
typedef float v4f __attribute__((ext_vector_type(4)));
typedef float v16f __attribute__((ext_vector_type(16)));

__device__ __forceinline__ unsigned short f2h_u(float x) {
  _Float16 h = (_Float16)x;
  union { _Float16 h; unsigned short u; } v; v.h = h; return v.u;
}
__device__ __forceinline__ unsigned short bf16t(float x) {
  union { float f; unsigned int u; } v; v.f = x; return (unsigned short)(v.u >> 16);
}
__device__ __forceinline__ float bf16tof(unsigned short s) {
  union { unsigned int u; float f; } v; v.u = ((unsigned int)s) << 16; return v.f;
}

// ================= K1: prep (multi-block) =================
__global__ __launch_bounds__(256) void k_prep(
    const float* __restrict__ mask1, const float* __restrict__ mask2,
    const float* __restrict__ conv_w, const float* __restrict__ conv_b,
    const float* __restrict__ bn_gamma, const float* __restrict__ bn_beta,
    const float* __restrict__ bn_mean, const float* __restrict__ bn_var,
    const float* __restrict__ attn_w1, const float* __restrict__ cls_w1,
    float* __restrict__ wsf, unsigned short* __restrict__ w1t,
    unsigned short* __restrict__ cw1h, unsigned short* __restrict__ cw1l)
{
  const int gid = blockIdx.x * 256 + threadIdx.x;
  const int gsz = gridDim.x * 256;
  float* m1 = wsf + WS_M1_F;
  float* m2 = wsf + WS_M2_F;
  float* bnsc = wsf + WS_BNSC_F;
  float* bnsh = wsf + WS_BNSH_F;
  float* wT = wsf + WS_WT_F;
  for (int e = gid; e < 4096; e += gsz) {
    int i = e >> 6, j = e & 63;
    float s1 = mask1[e] + mask1[j * 64 + i];
    float s2 = mask2[e] + mask2[j * 64 + i];
    m1[e] = 0.5f / (1.f + expf(-s1));
    m2[e] = 0.5f / (1.f + expf(-s2));
  }
  for (int e = gid; e < 64; e += gsz) {
    float sc = bn_gamma[e] * rsqrtf(bn_var[e] + 1e-5f);
    bnsc[e] = sc;
    bnsh[e] = (conv_b[e] - bn_mean[e]) * sc + bn_beta[e];
  }
  for (int e = gid; e < 12288; e += gsz) {
    int o = e / 192, ik = e % 192;
    wT[ik * 64 + o] = conv_w[e];
  }
  for (int e = gid; e < 65536; e += gsz) {
    int n = e >> 11, i = e & 2047;
    w1t[e] = f2h_u(attn_w1[i * 32 + n]);
  }
  for (int e = gid; e < 262144; e += gsz) {
    int n = e >> 11, k = e & 2047;
    float x = cls_w1[k * 128 + n];
    unsigned short h = bf16t(x);
    cw1h[e] = h;
    cw1l[e] = bf16t(x - bf16tof(h));
  }
}

// ===== K2: fused conv+BN -> recurrence -> attention, one block per batch =====
// 256 threads (4 waves). LDS: pots_s 65536 B + smR 11776 B = 77312 B
// -> 2 blocks/CU. Row 15 of pots_s ZEROED at start (replay determinism).
// The softmax-weight broadcast uses register shuffles, NOT LDS: the old
// wbuf same-wave RAW-without-barrier was codegen-fragile (compiler could
// hoist the reads above the conditional write) and caused per-binary
// correctness lottery in rounds 6-8.
__global__ __launch_bounds__(256) void k_fused(
    const float* __restrict__ L_norm, const float* __restrict__ X_seq,
    const float* __restrict__ gcn1_w, const float* __restrict__ gcn1_b,
    const float* __restrict__ gcn2_w, const float* __restrict__ gcn2_b,
    const float* __restrict__ beta2p, const float* __restrict__ wsf,
    const unsigned short* __restrict__ w1t,
    const float* __restrict__ attn_b1, const float* __restrict__ attn_w2,
    const float* __restrict__ attn_b2,
    unsigned short* __restrict__ ctxh, unsigned short* __restrict__ ctxl,
    int b0)
{
  __shared__ __align__(16) unsigned short pots_s[16 * 2048];
  __shared__ __align__(16) char smR[11776];
  float* xcur = (float*)smR;                          // 960 f32   [0,3840)
  float* zp = (float*)(smR + 3840);                   // 128 f32   [3840,4352)
  unsigned short* spk1T = (unsigned short*)(smR + 4352); // 16*72 u16 [4352,6656)
  float* Z2f = (float*)(smR + 6656);                  // 64*20 f32 [6656,11776)

  const int tid = threadIdx.x;
  const int lane = tid & 63;
  const int wv = tid >> 6;
  const int b = b0 + blockIdx.x;

  const float* m1 = wsf + WS_M1_F;
  const float* m2 = wsf + WS_M2_F;

  // ---- phase A: conv + BN (xraw staged in pots_s area, dead until t=1) ----
  {
    float* xraw = (float*)pots_s;
    for (int e = tid; e < 960; e += 256) xraw[e] = X_seq[(size_t)b * 960 + e];
    // zero pots_s row 15 (feeds the discarded t=15 MFMA A-row): determinism
    *(uint4*)&pots_s[15 * 2048 + tid * 8] = make_uint4(0u, 0u, 0u, 0u);
    __syncthreads();
    const float* bnsc = wsf + WS_BNSC_F;
    const float* bnsh = wsf + WS_BNSH_F;
    const float* wT = wsf + WS_WT_F;
    const int o = lane;
    const int t0 = wv, t1 = wv + 4, t2 = wv + 8, t3 = wv + 12;
    float a0 = 0.f, a1 = 0.f, a2 = 0.f, a3 = 0.f;
    for (int i = 0; i < 64; ++i) {
      const float w0 = wT[(3 * i + 0) * 64 + o];
      const float w1 = wT[(3 * i + 1) * 64 + o];
      const float w2 = wT[(3 * i + 2) * 64 + o];
      float xa = (t0 >= 2) ? xraw[(t0 - 2) * 64 + i] : 0.f;
      float xb = (t0 >= 1) ? xraw[(t0 - 1) * 64 + i] : 0.f;
      a0 += w0 * xa + w1 * xb + w2 * xraw[t0 * 64 + i];
      a1 += w0 * xraw[(t1 - 2) * 64 + i] + w1 * xraw[(t1 - 1) * 64 + i] + w2 * xraw[t1 * 64 + i];
      a2 += w0 * xraw[(t2 - 2) * 64 + i] + w1 * xraw[(t2 - 1) * 64 + i] + w2 * xraw[t2 * 64 + i];
      if (t3 < 15)
        a3 += w0 * xraw[(t3 - 2) * 64 + i] + w1 * xraw[(t3 - 1) * 64 + i] + w2 * xraw[t3 * 64 + i];
    }
    const float sc = bnsc[o], sh = bnsh[o];
    xcur[t0 * 64 + o] = a0 * sc + sh;
    xcur[t1 * 64 + o] = a1 * sc + sh;
    xcur[t2 * 64 + o] = a2 * sc + sh;
    if (t3 < 15) xcur[t3 * 64 + o] = a3 * sc + sh;
    __syncthreads();
  }

  // ---- phase B: register prep ----
  float L1h[32];
  const int kb1 = (wv & 1) * 32;
  if (wv >= 2) {
    const float* Lb = L_norm + (size_t)b * 4096 + lane * 64 + kb1;
    const float* mr = m1 + lane * 64 + kb1;
#pragma unroll
    for (int q4 = 0; q4 < 8; ++q4) {
      float4 lv = *(const float4*)(Lb + 4 * q4);
      float4 mv = *(const float4*)(mr + 4 * q4);
      L1h[4 * q4 + 0] = lv.x * mv.x;
      L1h[4 * q4 + 1] = lv.y * mv.y;
      L1h[4 * q4 + 2] = lv.z * mv.z;
      L1h[4 * q4 + 3] = lv.w * mv.w;
    }
  }

  v8s A_hi[2], A_lo[2];
  {
    const int irow = wv * 16 + (lane & 15);
    const int quad = (lane >> 4) & 3;
#pragma unroll
    for (int kb = 0; kb < 2; ++kb) {
      const float* Lb = L_norm + (size_t)b * 4096 + irow * 64 + kb * 32 + quad * 8;
      const float* mr = m2 + irow * 64 + kb * 32 + quad * 8;
      float4 la = *(const float4*)Lb, lb2 = *(const float4*)(Lb + 4);
      float4 ma = *(const float4*)mr, mb = *(const float4*)(mr + 4);
      float v[8] = { la.x * ma.x, la.y * ma.y, la.z * ma.z, la.w * ma.w,
                     lb2.x * mb.x, lb2.y * mb.y, lb2.z * mb.z, lb2.w * mb.w };
#pragma unroll
      for (int e = 0; e < 8; ++e) {
        unsigned short h = bf16t(v[e]);
        unsigned short l = bf16t(v[e] - bf16tof(h));
        A_hi[kb][e] = (short)h;
        A_lo[kb][e] = (short)l;
      }
    }
  }

  v8s W_hi, W_lo;
  {
    const int n = lane & 31;
    const int kh = (lane >> 5) & 1;
#pragma unroll
    for (int e = 0; e < 8; ++e) {
      float x = gcn2_w[(kh * 8 + e) * 32 + n];
      unsigned short h = bf16t(x);
      unsigned short l = bf16t(x - bf16tof(h));
      W_hi[e] = (short)h;
      W_lo[e] = (short)l;
    }
  }

  const float b2h = gcn2_b[lane & 31];
  const int np = tid >> 3;
  const int cp = tid & 7;
  float w1c[2], b1c[2];
#pragma unroll
  for (int d = 0; d < 2; ++d) { w1c[d] = gcn1_w[2 * cp + d]; b1c[d] = gcn1_b[2 * cp + d]; }
  const float beta2 = beta2p[0];

  float mem_t = 0.f;
  float mg1[4] = {0.f, 0.f, 0.f, 0.f};
  v16f mg2;
#pragma unroll
  for (int r = 0; r < 16; ++r) mg2[r] = 0.f;

  auto stage_b = [&](int tm1) {
    const int m = lane & 31;
    const int half = lane >> 5;
    const float* zr = Z2f + (wv * 32 + m) * 20 + half * 8;
    float4 za = *(const float4*)zr;
    float4 zb = *(const float4*)(zr + 4);
    float vv[8] = {za.x, za.y, za.z, za.w, zb.x, zb.y, zb.z, zb.w};
    v8s Ah, Al;
#pragma unroll
    for (int e = 0; e < 8; ++e) {
      unsigned short h = bf16t(vv[e]);
      unsigned short l = bf16t(vv[e] - bf16tof(h));
      Ah[e] = (short)h;
      Al[e] = (short)l;
    }
    v16f acc;
#pragma unroll
    for (int r = 0; r < 16; ++r) {
      float rs = (mg2[r] > 1.f) ? 1.f : 0.f;
      acc[r] = fmaf(beta2, mg2[r], b2h - rs);
    }
    acc = __builtin_amdgcn_mfma_f32_32x32x16_bf16(Ah, W_hi, acc, 0, 0, 0);
    acc = __builtin_amdgcn_mfma_f32_32x32x16_bf16(Al, W_hi, acc, 0, 0, 0);
    acc = __builtin_amdgcn_mfma_f32_32x32x16_bf16(Ah, W_lo, acc, 0, 0, 0);
    mg2 = acc;
    const int xorv = (tm1 & 7) << 3;
    const int base = tm1 * 2048 + m;
#pragma unroll
    for (int r = 0; r < 16; ++r) {
      int i = wv * 32 + (r & 3) + 8 * (r >> 2) + 4 * half;
      pots_s[(base + i * 32) ^ xorv] = f2h_u(acc[r]);
    }
  };

  // ---- phase C: 15-step recurrence ----
  for (int t = 0; t < 15; ++t) {
    if (wv >= 2) {
      float xc = xcur[t * 64 + lane];
      float rs = (mem_t > 1.f) ? 1.f : 0.f;
      mem_t = 0.9f * mem_t + xc - rs;
      float sp = (mem_t > 1.f) ? 1.f : 0.f;
      int spi = __float_as_int(sp);
      float zh = 0.f;
#pragma unroll
      for (int k = 0; k < 32; ++k) {
        float s = __int_as_float(__builtin_amdgcn_readlane(spi, kb1 + k));
        zh = fmaf(s, L1h[k], zh);
      }
      zp[(wv & 1) * 64 + lane] = zh;
    } else if (t > 0) {
      stage_b(t - 1);
    }
    __syncthreads();
    {
      float2 q0 = *(const float2*)&zp[2 * np];
      float2 q1 = *(const float2*)&zp[64 + 2 * np];
      float z0 = q0.x + q1.x;
      float z1v = q0.y + q1.y;
#pragma unroll
      for (int d = 0; d < 2; ++d) {
        float cur0 = fmaf(z0, w1c[d], b1c[d]);
        float rs0 = (mg1[d * 2 + 0] > 1.f) ? 1.f : 0.f;
        mg1[d * 2 + 0] = 0.85f * mg1[d * 2 + 0] + cur0 - rs0;
        unsigned int bits0 = (mg1[d * 2 + 0] > 1.f) ? 0x3F80u : 0u;
        float cur1 = fmaf(z1v, w1c[d], b1c[d]);
        float rs1 = (mg1[d * 2 + 1] > 1.f) ? 1.f : 0.f;
        mg1[d * 2 + 1] = 0.85f * mg1[d * 2 + 1] + cur1 - rs1;
        unsigned int bits1 = (mg1[d * 2 + 1] > 1.f) ? 0x3F80u : 0u;
        *(unsigned int*)&spk1T[(2 * cp + d) * 72 + 2 * np] = bits0 | (bits1 << 16);
      }
    }
    __syncthreads();
    {
      const int c = lane & 15;
      const int quad = (lane >> 4) & 3;
      const unsigned short* bp = spk1T + c * 72 + quad * 8;
      v8s B0 = *(const v8s*)(bp);
      v8s B1 = *(const v8s*)(bp + 32);
      v4f acc = {0.f, 0.f, 0.f, 0.f};
      acc = __builtin_amdgcn_mfma_f32_16x16x32_bf16(A_hi[0], B0, acc, 0, 0, 0);
      acc = __builtin_amdgcn_mfma_f32_16x16x32_bf16(A_lo[0], B0, acc, 0, 0, 0);
      acc = __builtin_amdgcn_mfma_f32_16x16x32_bf16(A_hi[1], B1, acc, 0, 0, 0);
      acc = __builtin_amdgcn_mfma_f32_16x16x32_bf16(A_lo[1], B1, acc, 0, 0, 0);
      const int r0 = wv * 16 + quad * 4;
#pragma unroll
      for (int r = 0; r < 4; ++r) Z2f[(r0 + r) * 20 + c] = acc[r];
    }
    __syncthreads();
  }
  if (wv < 2) stage_b(14);
  __syncthreads();   // pots_s complete; smR free for sred overlay

  // ---- phase D: attention (scores + softmax + ctx) from LDS pots ----
  float* sred = (float*)smR;            // 8*256 f32 (overlays xcur/zp/spk1T/Z2f)
  const int m = lane & 15;
  const int quad = lane >> 4;
  const int koff = quad * 8;

  v4f a0 = {0.f, 0.f, 0.f, 0.f}, a1 = {0.f, 0.f, 0.f, 0.f};
  {
    const int axor = (m & 7) << 3;      // row 15 zeroed -> deterministic
    const int abase = m * 2048 + koff;
    const unsigned short* B0p = w1t + (size_t)m * 2048 + koff;
    const unsigned short* B1p = w1t + (size_t)(m + 16) * 2048 + koff;
#pragma unroll 4
    for (int c = wv * 16; c < wv * 16 + 16; ++c) {
      v8h A = *(const v8h*)(pots_s + ((abase + c * 32) ^ axor));
      v8h B0 = *(const v8h*)(B0p + c * 32);
      v8h B1 = *(const v8h*)(B1p + c * 32);
      a0 = __builtin_amdgcn_mfma_f32_16x16x32_f16(A, B0, a0, 0, 0, 0);
      a1 = __builtin_amdgcn_mfma_f32_16x16x32_f16(A, B1, a1, 0, 0, 0);
    }
  }
#pragma unroll
  for (int j = 0; j < 4; ++j) {
    sred[j * 256 + tid] = a0[j];
    sred[(j + 4) * 256 + tid] = a1[j];
  }
  __syncthreads();
  float s0[4], s1[4];
#pragma unroll
  for (int j = 0; j < 4; ++j) {
    s0[j] = sred[j * 256 + 0 * 64 + lane] + sred[j * 256 + 1 * 64 + lane]
          + sred[j * 256 + 2 * 64 + lane] + sred[j * 256 + 3 * 64 + lane];
    s1[j] = sred[(j + 4) * 256 + 0 * 64 + lane] + sred[(j + 4) * 256 + 1 * 64 + lane]
          + sred[(j + 4) * 256 + 2 * 64 + lane] + sred[(j + 4) * 256 + 3 * 64 + lane];
  }
  float wlar[16];
  {
    const int n = m;
    const float b1a = attn_b1[n], b1b = attn_b1[n + 16];
    const float w2a = attn_w2[n], w2b = attn_w2[n + 16];
    const float b2 = attn_b2[0];
    float sc[4];
#pragma unroll
    for (int r = 0; r < 4; ++r) {
      float v = tanhf(s0[r] + b1a) * w2a + tanhf(s1[r] + b1b) * w2b;
      v += __shfl_xor(v, 1, 64);
      v += __shfl_xor(v, 2, 64);
      v += __shfl_xor(v, 4, 64);
      v += __shfl_xor(v, 8, 64);
      sc[r] = v + b2;
    }
    float mx = -1e30f;
#pragma unroll
    for (int r = 0; r < 4; ++r) if (quad * 4 + r < 15) mx = fmaxf(mx, sc[r]);
    mx = fmaxf(mx, __shfl_xor(mx, 16, 64));
    mx = fmaxf(mx, __shfl_xor(mx, 32, 64));
    float e[4], den = 0.f;
#pragma unroll
    for (int r = 0; r < 4; ++r) {
      e[r] = (quad * 4 + r < 15) ? expf(sc[r] - mx) : 0.f;
      den += e[r];
    }
    den += __shfl_xor(den, 16, 64);
    den += __shfl_xor(den, 32, 64);
    const float inv = 1.f / den;
    // Broadcast each quad-group's e[0..3] to all lanes via register
    // shuffles. e[r] is uniform within a 16-lane quad-group, so lane q4*16
    // is a valid source for quad q4. Replaces the LDS wbuf RAW (race).
#pragma unroll
    for (int q4 = 0; q4 < 4; ++q4) {
#pragma unroll
      for (int r = 0; r < 4; ++r) {
        wlar[q4 * 4 + r] = __shfl(e[r], q4 * 16, 64) * inv;
      }
    }
  }
  // ctx = sum_t w_t * pots[t] (swizzled LDS rows, conflict-free)
  float cv[8] = {0.f, 0.f, 0.f, 0.f, 0.f, 0.f, 0.f, 0.f};
#pragma unroll
  for (int t = 0; t < 15; ++t) {
    const int idx = (t * 2048 + tid * 8) ^ ((t & 7) << 3);
    v8h pv = *(const v8h*)(pots_s + idx);
    const float w = wlar[t];
#pragma unroll
    for (int j = 0; j < 8; ++j) cv[j] = fmaf(w, (float)pv[j], cv[j]);
  }
  unsigned short hv[8], lv[8];
#pragma unroll
  for (int j = 0; j < 8; ++j) {
    unsigned short h = bf16t(cv[j]);
    hv[j] = h;
    lv[j] = bf16t(cv[j] - bf16tof(h));
  }
  *(uint4*)(ctxh + (size_t)blockIdx.x * 2048 + tid * 8) = *(const uint4*)hv;
  *(uint4*)(ctxl + (size_t)blockIdx.x * 2048 + tid * 8) = *(const uint4*)lv;
}

// ================= K4: classifier, MFMA bf16 hi/lo =================
__global__ __launch_bounds__(256) void k_cls(
    const unsigned short* __restrict__ ctxh, const unsigned short* __restrict__ ctxl,
    const unsigned short* __restrict__ cw1h, const unsigned short* __restrict__ cw1l,
    const float* __restrict__ cls_b1,
    const float* __restrict__ ln_g, const float* __restrict__ ln_b,
    const float* __restrict__ cls_w2, const float* __restrict__ cls_b2,
    float* __restrict__ out, int b0)
{
  __shared__ float hbuf[16 * 132];
  const int tid = threadIdx.x;
  const int lane = tid & 63;
  const int wv = tid >> 6;
  const int m = lane & 15;
  const int quad = lane >> 4;
  const int koff = quad * 8;
  const int r0l = blockIdx.x * 16;

  v4f a0 = {0.f, 0.f, 0.f, 0.f}, a1 = {0.f, 0.f, 0.f, 0.f};
  {
    const unsigned short* Ah = ctxh + (size_t)(r0l + m) * 2048;
    const unsigned short* Al = ctxl + (size_t)(r0l + m) * 2048;
    const int n0 = wv * 32 + m;
    const unsigned short* B0h = cw1h + (size_t)n0 * 2048;
    const unsigned short* B0l = cw1l + (size_t)n0 * 2048;
    const unsigned short* B1h = cw1h + (size_t)(n0 + 16) * 2048;
    const unsigned short* B1l = cw1l + (size_t)(n0 + 16) * 2048;
#pragma unroll 4
    for (int kc = 0; kc < 64; ++kc) {
      const int kb = kc * 32 + koff;
      v8s vAh = *(const v8s*)(Ah + kb);
      v8s vAl = *(const v8s*)(Al + kb);
      v8s vB0h = *(const v8s*)(B0h + kb);
      v8s vB0l = *(const v8s*)(B0l + kb);
      v8s vB1h = *(const v8s*)(B1h + kb);
      v8s vB1l = *(const v8s*)(B1l + kb);
      a0 = __builtin_amdgcn_mfma_f32_16x16x32_bf16(vAh, vB0h, a0, 0, 0, 0);
      a0 = __builtin_amdgcn_mfma_f32_16x16x32_bf16(vAl, vB0h, a0, 0, 0, 0);
      a0 = __builtin_amdgcn_mfma_f32_16x16x32_bf16(vAh, vB0l, a0, 0, 0, 0);
      a1 = __builtin_amdgcn_mfma_f32_16x16x32_bf16(vAh, vB1h, a1, 0, 0, 0);
      a1 = __builtin_amdgcn_mfma_f32_16x16x32_bf16(vAl, vB1h, a1, 0, 0, 0);
      a1 = __builtin_amdgcn_mfma_f32_16x16x32_bf16(vAh, vB1l, a1, 0, 0, 0);
    }
  }
  {
    const int n0 = wv * 32 + m;
    const float bb0 = cls_b1[n0], bb1 = cls_b1[n0 + 16];
#pragma unroll
    for (int r = 0; r < 4; ++r) {
      const int row = quad * 4 + r;
      hbuf[row * 132 + n0] = a0[r] + bb0;
      hbuf[row * 132 + n0 + 16] = a1[r] + bb1;
    }
  }
  __syncthreads();
  const float g0c = ln_g[lane], g1c = ln_g[lane + 64];
  const float b0c = ln_b[lane], b1c = ln_b[lane + 64];
  const float4 w2a = *(const float4*)(cls_w2 + lane * 4);
  const float4 w2b = *(const float4*)(cls_w2 + (lane + 64) * 4);
#pragma unroll
  for (int rr = 0; rr < 4; ++rr) {
    const int r = wv * 4 + rr;
    const float x0 = hbuf[r * 132 + lane];
    const float x1 = hbuf[r * 132 + 64 + lane];
    float s = x0 + x1, sq = x0 * x0 + x1 * x1;
#pragma unroll
    for (int mm = 32; mm >= 1; mm >>= 1) {
      s += __shfl_xor(s, mm, 64);
      sq += __shfl_xor(sq, mm, 64);
    }
    const float mu = s * (1.f / 128.f);
    const float var = sq * (1.f / 128.f) - mu * mu;
    const float rstd = rsqrtf(var + 1e-5f);
    float h0 = (x0 - mu) * rstd * g0c + b0c;
    float h1 = (x1 - mu) * rstd * g1c + b1c;
    h0 = 0.5f * h0 * (1.f + erff(h0 * 0.7071067811865475f));
    h1 = 0.5f * h1 * (1.f + erff(h1 * 0.7071067811865475f));
    float o0 = h0 * w2a.x + h1 * w2b.x;
    float o1 = h0 * w2a.y + h1 * w2b.y;
    float o2 = h0 * w2a.z + h1 * w2b.z;
    float o3 = h0 * w2a.w + h1 * w2b.w;
#pragma unroll
    for (int mm = 32; mm >= 1; mm >>= 1) {
      o0 += __shfl_xor(o0, mm, 64);
      o1 += __shfl_xor(o1, mm, 64);
      o2 += __shfl_xor(o2, mm, 64);
      o3 += __shfl_xor(o3, mm, 64);
    }
    if (lane == 0) {
      *(float4*)(out + (size_t)(b0 + r0l + r) * 4) =
          make_float4(o0 + cls_b2[0], o1 + cls_b2[1], o2 + cls_b2[2], o3 + cls_b2[3]);
    }
  }
}

// ================= host =================
extern "C" void kernel_launch(void* const* d_in, const int* in_sizes, int n_in,
                              void* d_out, int out_size, void* d_ws, size_t ws_size,
                              hipStream_t stream) {
  const float* L_norm   = (const float*)d_in[0];
  const float* X_seq    = (const float*)d_in[1];
  const float* conv_w   = (const float*)d_in[2];
  const float* conv_b   = (const float*)d_in[3];
  const float* bn_gamma = (const float*)d_in[4];
  const float* bn_beta  = (const float*)d_in[5];
  const float* bn_mean  = (const float*)d_in[6];
  const float* bn_var   = (const float*)d_in[7];
  const float* gcn1_w   = (const float*)d_in[8];
  const float* gcn1_b   = (const float*)d_in[9];
  const float* mask1    = (const float*)d_in[10];
  const float* gcn2_w   = (const float*)d_in[11];
  const float* gcn2_b   = (const float*)d_in[12];
  const float* mask2    = (const float*)d_in[13];
  const float* beta2    = (const float*)d_in[14];
  const float* attn_w1  = (const float*)d_in[15];
  const float* attn_b1  = (const float*)d_in[16];
  const float* attn_w2  = (const float*)d_in[17];
  const float* attn_b2  = (const float*)d_in[18];
  const float* cls_w1   = (const float*)d_in[19];
  const float* cls_b1   = (const float*)d_in[20];
  const float* ln_gamma = (const float*)d_in[21];
  const float* ln_beta  = (const float*)d_in[22];
  const float* cls_w2   = (const float*)d_in[23];
  const float* cls_b2   = (const float*)d_in[24];

  char* ws = (char*)d_ws;
  float* wsf = (float*)d_ws;
  unsigned short* w1t  = (unsigned short*)(ws + OFF_W1T);
  unsigned short* cw1h = (unsigned short*)(ws + OFF_CW1H);
  unsigned short* cw1l = (unsigned short*)(ws + OFF_CW1L);

  // ctx hi/lo planes only (pots lives in LDS); 8192 B per batch
  long long avail = (long long)ws_size - (long long)OFF_CTX;
  int chunk = 4096;
  if (avail < 8192LL * 4096LL) {
    long long c = (avail > 0) ? (avail / 8192) : 64;
    if (c > 4096) c = 4096;
    c &= ~63LL;
    if (c < 64) c = 64;
    chunk = (int)c;
  }
  unsigned short* ctxh = (unsigned short*)(ws + OFF_CTX);
  unsigned short* ctxl = ctxh + (size_t)chunk * 2048;

  hipLaunchKernelGGL(k_prep, dim3(64), dim3(256), 0, stream,
                     mask1, mask2, conv_w, conv_b, bn_gamma, bn_beta, bn_mean, bn_var,
                     attn_w1, cls_w1, wsf, w1t, cw1h, cw1l);

  for (int b0 = 0; b0 < 4096; b0 += chunk) {
    int cur = 4096 - b0;
    if (cur > chunk) cur = chunk;
    hipLaunchKernelGGL(k_fused, dim3(cur), dim3(256), 0, stream,
                       L_norm, X_seq, gcn1_w, gcn1_b, gcn2_w, gcn2_b, beta2,
                       wsf, w1t, attn_b1, attn_w2, attn_b2, ctxh, ctxl, b0);
    hipLaunchKernelGGL(k_cls, dim3(cur / 16), dim3(256), 0, stream,
                       ctxh, ctxl, cw1h, cw1l, cls_b1, ln_gamma, ln_beta, cls_w2, cls_b2,
                       (float*)d_out, b0);
  }
}

// Round 10
// 496.138 us; speedup vs baseline: 1.3524x; 1.0104x over previous
//
#include <hip/hip_runtime.h>
#include <math.h>

// ---------------- workspace layout (bytes unless _F) ----------------
#define WS_M1_F    0           // 4096 f32
#define WS_M2_F    4096        // 4096 f32
#define WS_BNSC_F  8192        // 64 f32
#define WS_BNSH_F  8256        // 64 f32
#define WS_WT_F    8448        // 12288 f32 (conv_w transposed [ik][o])
#define OFF_W1T    83968       // u16[32*2048]  attn_w1^T fp16  -> +131072 = 215040
#define OFF_CW1H   215040      // u16[128*2048] cls_w1^T bf16-hi -> +524288 = 739328
#define OFF_CW1L   739328      // u16[128*2048] cls_w1^T bf16-lo -> +524288 = 1263616
#define OFF_CTX    1263616     // per-chunk ctx hi/lo planes (8192 B/batch)

typedef _Float16 v8h __attribute__((ext_vector_type(8)));
typedef short v8s __attribute__((ext_vector_type(8)));
typedef float v4f __attribute__((ext_vector_type(4)));
typedef float v16f __attribute__((ext_vector_type(16)));

__device__ __forceinline__ unsigned short f2h_u(float x) {
  _Float16 h = (_Float16)x;
  union { _Float16 h; unsigned short u; } v; v.h = h; return v.u;
}
__device__ __forceinline__ unsigned short bf16t(float x) {
  union { float f; unsigned int u; } v; v.f = x; return (unsigned short)(v.u >> 16);
}
__device__ __forceinline__ float bf16tof(unsigned short s) {
  union { unsigned int u; float f; } v; v.u = ((unsigned int)s) << 16; return v.f;
}

// ================= K1: prep (multi-block) =================
__global__ __launch_bounds__(256) void k_prep(
    const float* __restrict__ mask1, const float* __restrict__ mask2,
    const float* __restrict__ conv_w, const float* __restrict__ conv_b,
    const float* __restrict__ bn_gamma, const float* __restrict__ bn_beta,
    const float* __restrict__ bn_mean, const float* __restrict__ bn_var,
    const float* __restrict__ attn_w1, const float* __restrict__ cls_w1,
    float* __restrict__ wsf, unsigned short* __restrict__ w1t,
    unsigned short* __restrict__ cw1h, unsigned short* __restrict__ cw1l)
{
  const int gid = blockIdx.x * 256 + threadIdx.x;
  const int gsz = gridDim.x * 256;
  float* m1 = wsf + WS_M1_F;
  float* m2 = wsf + WS_M2_F;
  float* bnsc = wsf + WS_BNSC_F;
  float* bnsh = wsf + WS_BNSH_F;
  float* wT = wsf + WS_WT_F;
  for (int e = gid; e < 4096; e += gsz) {
    int i = e >> 6, j = e & 63;
    float s1 = mask1[e] + mask1[j * 64 + i];
    float s2 = mask2[e] + mask2[j * 64 + i];
    m1[e] = 0.5f / (1.f + expf(-s1));
    m2[e] = 0.5f / (1.f + expf(-s2));
  }
  for (int e = gid; e < 64; e += gsz) {
    float sc = bn_gamma[e] * rsqrtf(bn_var[e] + 1e-5f);
    bnsc[e] = sc;
    bnsh[e] = (conv_b[e] - bn_mean[e]) * sc + bn_beta[e];
  }
  for (int e = gid; e < 12288; e += gsz) {
    int o = e / 192, ik = e % 192;
    wT[ik * 64 + o] = conv_w[e];
  }
  for (int e = gid; e < 65536; e += gsz) {
    int n = e >> 11, i = e & 2047;
    w1t[e] = f2h_u(attn_w1[i * 32 + n]);
  }
  for (int e = gid; e < 262144; e += gsz) {
    int n = e >> 11, k = e & 2047;
    float x = cls_w1[k * 128 + n];
    unsigned short h = bf16t(x);
    cw1h[e] = h;
    cw1l[e] = bf16t(x - bf16tof(h));
  }
}

// ===== K2: fused conv+BN -> recurrence -> attention, one block per batch =====
// 256 threads (4 waves). LDS: pots_s 65536 B + smR 11776 B = 77312 B
// -> 2 blocks/CU. Row 15 of pots_s ZEROED at start (replay determinism).
// Softmax-weight broadcast is register shuffles, NOT LDS (the old wbuf
// same-wave RAW-without-barrier was a codegen-dependent race; rounds 6-8).
__global__ __launch_bounds__(256) void k_fused(
    const float* __restrict__ L_norm, const float* __restrict__ X_seq,
    const float* __restrict__ gcn1_w, const float* __restrict__ gcn1_b,
    const float* __restrict__ gcn2_w, const float* __restrict__ gcn2_b,
    const float* __restrict__ beta2p, const float* __restrict__ wsf,
    const unsigned short* __restrict__ w1t,
    const float* __restrict__ attn_b1, const float* __restrict__ attn_w2,
    const float* __restrict__ attn_b2,
    unsigned short* __restrict__ ctxh, unsigned short* __restrict__ ctxl,
    int b0)
{
  __shared__ __align__(16) unsigned short pots_s[16 * 2048];
  __shared__ __align__(16) char smR[11776];
  float* xcur = (float*)smR;                          // 960 f32   [0,3840)
  float* zp = (float*)(smR + 3840);                   // 128 f32   [3840,4352)
  unsigned short* spk1T = (unsigned short*)(smR + 4352); // 16*72 u16 [4352,6656)
  float* Z2f = (float*)(smR + 6656);                  // 64*20 f32 [6656,11776)

  const int tid = threadIdx.x;
  const int lane = tid & 63;
  const int wv = tid >> 6;
  const int b = b0 + blockIdx.x;

  const float* m1 = wsf + WS_M1_F;
  const float* m2 = wsf + WS_M2_F;

  // ---- phase A: conv + BN (xraw staged in pots_s area, dead until t=1) ----
  {
    float* xraw = (float*)pots_s;
    for (int e = tid; e < 960; e += 256) xraw[e] = X_seq[(size_t)b * 960 + e];
    // zero pots_s row 15 (feeds the discarded t=15 MFMA A-row): determinism
    *(uint4*)&pots_s[15 * 2048 + tid * 8] = make_uint4(0u, 0u, 0u, 0u);
    __syncthreads();
    const float* bnsc = wsf + WS_BNSC_F;
    const float* bnsh = wsf + WS_BNSH_F;
    const float* wT = wsf + WS_WT_F;
    const int o = lane;
    const int t0 = wv, t1 = wv + 4, t2 = wv + 8, t3 = wv + 12;
    float a0 = 0.f, a1 = 0.f, a2 = 0.f, a3 = 0.f;
    for (int i = 0; i < 64; ++i) {
      const float w0 = wT[(3 * i + 0) * 64 + o];
      const float w1 = wT[(3 * i + 1) * 64 + o];
      const float w2 = wT[(3 * i + 2) * 64 + o];
      float xa = (t0 >= 2) ? xraw[(t0 - 2) * 64 + i] : 0.f;
      float xb = (t0 >= 1) ? xraw[(t0 - 1) * 64 + i] : 0.f;
      a0 += w0 * xa + w1 * xb + w2 * xraw[t0 * 64 + i];
      a1 += w0 * xraw[(t1 - 2) * 64 + i] + w1 * xraw[(t1 - 1) * 64 + i] + w2 * xraw[t1 * 64 + i];
      a2 += w0 * xraw[(t2 - 2) * 64 + i] + w1 * xraw[(t2 - 1) * 64 + i] + w2 * xraw[t2 * 64 + i];
      if (t3 < 15)
        a3 += w0 * xraw[(t3 - 2) * 64 + i] + w1 * xraw[(t3 - 1) * 64 + i] + w2 * xraw[t3 * 64 + i];
    }
    const float sc = bnsc[o], sh = bnsh[o];
    xcur[t0 * 64 + o] = a0 * sc + sh;
    xcur[t1 * 64 + o] = a1 * sc + sh;
    xcur[t2 * 64 + o] = a2 * sc + sh;
    if (t3 < 15) xcur[t3 * 64 + o] = a3 * sc + sh;
    __syncthreads();
  }

  // ---- phase B: register prep ----
  float L1h[32];
  const int kb1 = (wv & 1) * 32;
  if (wv >= 2) {
    const float* Lb = L_norm + (size_t)b * 4096 + lane * 64 + kb1;
    const float* mr = m1 + lane * 64 + kb1;
#pragma unroll
    for (int q4 = 0; q4 < 8; ++q4) {
      float4 lv = *(const float4*)(Lb + 4 * q4);
      float4 mv = *(const float4*)(mr + 4 * q4);
      L1h[4 * q4 + 0] = lv.x * mv.x;
      L1h[4 * q4 + 1] = lv.y * mv.y;
      L1h[4 * q4 + 2] = lv.z * mv.z;
      L1h[4 * q4 + 3] = lv.w * mv.w;
    }
  }

  v8s A_hi[2], A_lo[2];
  {
    const int irow = wv * 16 + (lane & 15);
    const int quad = (lane >> 4) & 3;
#pragma unroll
    for (int kb = 0; kb < 2; ++kb) {
      const float* Lb = L_norm + (size_t)b * 4096 + irow * 64 + kb * 32 + quad * 8;
      const float* mr = m2 + irow * 64 + kb * 32 + quad * 8;
      float4 la = *(const float4*)Lb, lb2 = *(const float4*)(Lb + 4);
      float4 ma = *(const float4*)mr, mb = *(const float4*)(mr + 4);
      float v[8] = { la.x * ma.x, la.y * ma.y, la.z * ma.z, la.w * ma.w,
                     lb2.x * mb.x, lb2.y * mb.y, lb2.z * mb.z, lb2.w * mb.w };
#pragma unroll
      for (int e = 0; e < 8; ++e) {
        unsigned short h = bf16t(v[e]);
        unsigned short l = bf16t(v[e] - bf16tof(h));
        A_hi[kb][e] = (short)h;
        A_lo[kb][e] = (short)l;
      }
    }
  }

  v8s W_hi, W_lo;
  {
    const int n = lane & 31;
    const int kh = (lane >> 5) & 1;
#pragma unroll
    for (int e = 0; e < 8; ++e) {
      float x = gcn2_w[(kh * 8 + e) * 32 + n];
      unsigned short h = bf16t(x);
      unsigned short l = bf16t(x - bf16tof(h));
      W_hi[e] = (short)h;
      W_lo[e] = (short)l;
    }
  }

  const float b2h = gcn2_b[lane & 31];
  const int np = tid >> 3;
  const int cp = tid & 7;
  float w1c[2], b1c[2];
#pragma unroll
  for (int d = 0; d < 2; ++d) { w1c[d] = gcn1_w[2 * cp + d]; b1c[d] = gcn1_b[2 * cp + d]; }
  const float beta2 = beta2p[0];

  float mem_t = 0.f;
  float mg1[4] = {0.f, 0.f, 0.f, 0.f};
  v16f mg2;
#pragma unroll
  for (int r = 0; r < 16; ++r) mg2[r] = 0.f;

  auto stage_b = [&](int tm1) {
    const int m = lane & 31;
    const int half = lane >> 5;
    const float* zr = Z2f + (wv * 32 + m) * 20 + half * 8;
    float4 za = *(const float4*)zr;
    float4 zb = *(const float4*)(zr + 4);
    float vv[8] = {za.x, za.y, za.z, za.w, zb.x, zb.y, zb.z, zb.w};
    v8s Ah, Al;
#pragma unroll
    for (int e = 0; e < 8; ++e) {
      unsigned short h = bf16t(vv[e]);
      unsigned short l = bf16t(vv[e] - bf16tof(h));
      Ah[e] = (short)h;
      Al[e] = (short)l;
    }
    v16f acc;
#pragma unroll
    for (int r = 0; r < 16; ++r) {
      float rs = (mg2[r] > 1.f) ? 1.f : 0.f;
      acc[r] = fmaf(beta2, mg2[r], b2h - rs);
    }
    acc = __builtin_amdgcn_mfma_f32_32x32x16_bf16(Ah, W_hi, acc, 0, 0, 0);
    acc = __builtin_amdgcn_mfma_f32_32x32x16_bf16(Al, W_hi, acc, 0, 0, 0);
    acc = __builtin_amdgcn_mfma_f32_32x32x16_bf16(Ah, W_lo, acc, 0, 0, 0);
    mg2 = acc;
    const int xorv = (tm1 & 7) << 3;
    const int base = tm1 * 2048 + m;
#pragma unroll
    for (int r = 0; r < 16; ++r) {
      int i = wv * 32 + (r & 3) + 8 * (r >> 2) + 4 * half;
      pots_s[(base + i * 32) ^ xorv] = f2h_u(acc[r]);
    }
  };

  // ---- phase C: 15-step recurrence ----
  for (int t = 0; t < 15; ++t) {
    if (wv >= 2) {
      float xc = xcur[t * 64 + lane];
      float rs = (mem_t > 1.f) ? 1.f : 0.f;
      mem_t = 0.9f * mem_t + xc - rs;
      float sp = (mem_t > 1.f) ? 1.f : 0.f;
      int spi = __float_as_int(sp);
      float zh = 0.f;
#pragma unroll
      for (int k = 0; k < 32; ++k) {
        float s = __int_as_float(__builtin_amdgcn_readlane(spi, kb1 + k));
        zh = fmaf(s, L1h[k], zh);
      }
      zp[(wv & 1) * 64 + lane] = zh;
    } else if (t > 0) {
      stage_b(t - 1);
    }
    __syncthreads();
    {
      float2 q0 = *(const float2*)&zp[2 * np];
      float2 q1 = *(const float2*)&zp[64 + 2 * np];
      float z0 = q0.x + q1.x;
      float z1v = q0.y + q1.y;
#pragma unroll
      for (int d = 0; d < 2; ++d) {
        float cur0 = fmaf(z0, w1c[d], b1c[d]);
        float rs0 = (mg1[d * 2 + 0] > 1.f) ? 1.f : 0.f;
        mg1[d * 2 + 0] = 0.85f * mg1[d * 2 + 0] + cur0 - rs0;
        unsigned int bits0 = (mg1[d * 2 + 0] > 1.f) ? 0x3F80u : 0u;
        float cur1 = fmaf(z1v, w1c[d], b1c[d]);
        float rs1 = (mg1[d * 2 + 1] > 1.f) ? 1.f : 0.f;
        mg1[d * 2 + 1] = 0.85f * mg1[d * 2 + 1] + cur1 - rs1;
        unsigned int bits1 = (mg1[d * 2 + 1] > 1.f) ? 0x3F80u : 0u;
        *(unsigned int*)&spk1T[(2 * cp + d) * 72 + 2 * np] = bits0 | (bits1 << 16);
      }
    }
    __syncthreads();
    {
      const int c = lane & 15;
      const int quad = (lane >> 4) & 3;
      const unsigned short* bp = spk1T + c * 72 + quad * 8;
      v8s B0 = *(const v8s*)(bp);
      v8s B1 = *(const v8s*)(bp + 32);
      v4f acc = {0.f, 0.f, 0.f, 0.f};
      acc = __builtin_amdgcn_mfma_f32_16x16x32_bf16(A_hi[0], B0, acc, 0, 0, 0);
      acc = __builtin_amdgcn_mfma_f32_16x16x32_bf16(A_lo[0], B0, acc, 0, 0, 0);
      acc = __builtin_amdgcn_mfma_f32_16x16x32_bf16(A_hi[1], B1, acc, 0, 0, 0);
      acc = __builtin_amdgcn_mfma_f32_16x16x32_bf16(A_lo[1], B1, acc, 0, 0, 0);
      const int r0 = wv * 16 + quad * 4;
#pragma unroll
      for (int r = 0; r < 4; ++r) Z2f[(r0 + r) * 20 + c] = acc[r];
    }
    __syncthreads();
  }
  if (wv < 2) stage_b(14);
  __syncthreads();   // pots_s complete; smR free for sred overlay

  // ---- phase D: attention (scores + softmax + ctx) from LDS pots ----
  float* sred = (float*)smR;            // 8*256 f32 (overlays xcur/zp/spk1T/Z2f)
  const int m = lane & 15;
  const int quad = lane >> 4;
  const int koff = quad * 8;

  v4f a0 = {0.f, 0.f, 0.f, 0.f}, a1 = {0.f, 0.f, 0.f, 0.f};
  {
    const int axor = (m & 7) << 3;      // row 15 zeroed -> deterministic
    const int abase = m * 2048 + koff;
    const unsigned short* B0p = w1t + (size_t)m * 2048 + koff;
    const unsigned short* B1p = w1t + (size_t)(m + 16) * 2048 + koff;
#pragma unroll 4
    for (int c = wv * 16; c < wv * 16 + 16; ++c) {
      v8h A = *(const v8h*)(pots_s + ((abase + c * 32) ^ axor));
      v8h B0 = *(const v8h*)(B0p + c * 32);
      v8h B1 = *(const v8h*)(B1p + c * 32);
      a0 = __builtin_amdgcn_mfma_f32_16x16x32_f16(A, B0, a0, 0, 0, 0);
      a1 = __builtin_amdgcn_mfma_f32_16x16x32_f16(A, B1, a1, 0, 0, 0);
    }
  }
#pragma unroll
  for (int j = 0; j < 4; ++j) {
    sred[j * 256 + tid] = a0[j];
    sred[(j + 4) * 256 + tid] = a1[j];
  }
  __syncthreads();
  float s0[4], s1[4];
#pragma unroll
  for (int j = 0; j < 4; ++j) {
    s0[j] = sred[j * 256 + 0 * 64 + lane] + sred[j * 256 + 1 * 64 + lane]
          + sred[j * 256 + 2 * 64 + lane] + sred[j * 256 + 3 * 64 + lane];
    s1[j] = sred[(j + 4) * 256 + 0 * 64 + lane] + sred[(j + 4) * 256 + 1 * 64 + lane]
          + sred[(j + 4) * 256 + 2 * 64 + lane] + sred[(j + 4) * 256 + 3 * 64 + lane];
  }
  float wlar[16];
  {
    const int n = m;
    const float b1a = attn_b1[n], b1b = attn_b1[n + 16];
    const float w2a = attn_w2[n], w2b = attn_w2[n + 16];
    const float b2 = attn_b2[0];
    float sc[4];
#pragma unroll
    for (int r = 0; r < 4; ++r) {
      float v = tanhf(s0[r] + b1a) * w2a + tanhf(s1[r] + b1b) * w2b;
      v += __shfl_xor(v, 1, 64);
      v += __shfl_xor(v, 2, 64);
      v += __shfl_xor(v, 4, 64);
      v += __shfl_xor(v, 8, 64);
      sc[r] = v + b2;
    }
    float mx = -1e30f;
#pragma unroll
    for (int r = 0; r < 4; ++r) if (quad * 4 + r < 15) mx = fmaxf(mx, sc[r]);
    mx = fmaxf(mx, __shfl_xor(mx, 16, 64));
    mx = fmaxf(mx, __shfl_xor(mx, 32, 64));
    float e[4], den = 0.f;
#pragma unroll
    for (int r = 0; r < 4; ++r) {
      e[r] = (quad * 4 + r < 15) ? expf(sc[r] - mx) : 0.f;
      den += e[r];
    }
    den += __shfl_xor(den, 16, 64);
    den += __shfl_xor(den, 32, 64);
    const float inv = 1.f / den;
    // Broadcast each quad-group's e[0..3] via register shuffles (race-free).
#pragma unroll
    for (int q4 = 0; q4 < 4; ++q4) {
#pragma unroll
      for (int r = 0; r < 4; ++r) {
        wlar[q4 * 4 + r] = __shfl(e[r], q4 * 16, 64) * inv;
      }
    }
  }
  // ctx = sum_t w_t * pots[t] (swizzled LDS rows, conflict-free)
  float cv[8] = {0.f, 0.f, 0.f, 0.f, 0.f, 0.f, 0.f, 0.f};
#pragma unroll
  for (int t = 0; t < 15; ++t) {
    const int idx = (t * 2048 + tid * 8) ^ ((t & 7) << 3);
    v8h pv = *(const v8h*)(pots_s + idx);
    const float w = wlar[t];
#pragma unroll
    for (int j = 0; j < 8; ++j) cv[j] = fmaf(w, (float)pv[j], cv[j]);
  }
  unsigned short hv[8], lv[8];
#pragma unroll
  for (int j = 0; j < 8; ++j) {
    unsigned short h = bf16t(cv[j]);
    hv[j] = h;
    lv[j] = bf16t(cv[j] - bf16tof(h));
  }
  *(uint4*)(ctxh + (size_t)blockIdx.x * 2048 + tid * 8) = *(const uint4*)hv;
  *(uint4*)(ctxl + (size_t)blockIdx.x * 2048 + tid * 8) = *(const uint4*)lv;
}

// ================= K4: classifier, MFMA bf16 hi/lo, 8-wave K-split =========
// Grid is capped at 256 blocks (m=16 batches per MFMA tile) = 1 block/CU, so
// wave-level parallelism is the only lever: 8 waves, waves 0-3 take kc 0..31,
// waves 4-7 take kc 32..63 (same n-mapping), partials summed through LDS.
// Halves the latency-exposed K-chain and doubles waves/SIMD (1 -> 2).
__global__ __launch_bounds__(512) void k_cls(
    const unsigned short* __restrict__ ctxh, const unsigned short* __restrict__ ctxl,
    const unsigned short* __restrict__ cw1h, const unsigned short* __restrict__ cw1l,
    const float* __restrict__ cls_b1,
    const float* __restrict__ ln_g, const float* __restrict__ ln_b,
    const float* __restrict__ cls_w2, const float* __restrict__ cls_b2,
    float* __restrict__ out, int b0)
{
  __shared__ float hbuf[16 * 132];       // 8448 B
  __shared__ __align__(16) float pred[256 * 8];  // 8192 B partials (waves 4-7)
  const int tid = threadIdx.x;
  const int lane = tid & 63;
  const int wv = tid >> 6;      // 0..7
  const int wq = wv & 3;        // n-group (matches old wv)
  const int kh = wv >> 2;       // K-half
  const int m = lane & 15;
  const int quad = lane >> 4;
  const int koff = quad * 8;
  const int r0l = blockIdx.x * 16;

  v4f a0 = {0.f, 0.f, 0.f, 0.f}, a1 = {0.f, 0.f, 0.f, 0.f};
  {
    const unsigned short* Ah = ctxh + (size_t)(r0l + m) * 2048;
    const unsigned short* Al = ctxl + (size_t)(r0l + m) * 2048;
    const int n0 = wq * 32 + m;
    const unsigned short* B0h = cw1h + (size_t)n0 * 2048;
    const unsigned short* B0l = cw1l + (size_t)n0 * 2048;
    const unsigned short* B1h = cw1h + (size_t)(n0 + 16) * 2048;
    const unsigned short* B1l = cw1l + (size_t)(n0 + 16) * 2048;
    const int kc0 = kh * 32;
#pragma unroll 4
    for (int kc = kc0; kc < kc0 + 32; ++kc) {
      const int kb = kc * 32 + koff;
      v8s vAh = *(const v8s*)(Ah + kb);
      v8s vAl = *(const v8s*)(Al + kb);
      v8s vB0h = *(const v8s*)(B0h + kb);
      v8s vB0l = *(const v8s*)(B0l + kb);
      v8s vB1h = *(const v8s*)(B1h + kb);
      v8s vB1l = *(const v8s*)(B1l + kb);
      a0 = __builtin_amdgcn_mfma_f32_16x16x32_bf16(vAh, vB0h, a0, 0, 0, 0);
      a0 = __builtin_amdgcn_mfma_f32_16x16x32_bf16(vAl, vB0h, a0, 0, 0, 0);
      a0 = __builtin_amdgcn_mfma_f32_16x16x32_bf16(vAh, vB0l, a0, 0, 0, 0);
      a1 = __builtin_amdgcn_mfma_f32_16x16x32_bf16(vAh, vB1h, a1, 0, 0, 0);
      a1 = __builtin_amdgcn_mfma_f32_16x16x32_bf16(vAl, vB1h, a1, 0, 0, 0);
      a1 = __builtin_amdgcn_mfma_f32_16x16x32_bf16(vAh, vB1l, a1, 0, 0, 0);
    }
  }
  // K-halves combine: waves 4-7 deposit, barrier, waves 0-3 add.
  if (kh == 1) {
    float* p = pred + (size_t)(wq * 64 + lane) * 8;
    *(v4f*)p = a0;
    *(v4f*)(p + 4) = a1;
  }
  __syncthreads();
  if (kh == 0) {
    const float* p = pred + (size_t)(wq * 64 + lane) * 8;
    v4f b0v = *(const v4f*)p;
    v4f b1v = *(const v4f*)(p + 4);
#pragma unroll
    for (int r = 0; r < 4; ++r) { a0[r] += b0v[r]; a1[r] += b1v[r]; }
    const int n0 = wq * 32 + m;
    const float bb0 = cls_b1[n0], bb1 = cls_b1[n0 + 16];
#pragma unroll
    for (int r = 0; r < 4; ++r) {
      const int row = quad * 4 + r;
      hbuf[row * 132 + n0] = a0[r] + bb0;
      hbuf[row * 132 + n0 + 16] = a1[r] + bb1;
    }
  }
  __syncthreads();
  if (kh == 0) {
    const float g0c = ln_g[lane], g1c = ln_g[lane + 64];
    const float b0c = ln_b[lane], b1c = ln_b[lane + 64];
    const float4 w2a = *(const float4*)(cls_w2 + lane * 4);
    const float4 w2b = *(const float4*)(cls_w2 + (lane + 64) * 4);
#pragma unroll
    for (int rr = 0; rr < 4; ++rr) {
      const int r = wq * 4 + rr;
      const float x0 = hbuf[r * 132 + lane];
      const float x1 = hbuf[r * 132 + 64 + lane];
      float s = x0 + x1, sq = x0 * x0 + x1 * x1;
#pragma unroll
      for (int mm = 32; mm >= 1; mm >>= 1) {
        s += __shfl_xor(s, mm, 64);
        sq += __shfl_xor(sq, mm, 64);
      }
      const float mu = s * (1.f / 128.f);
      const float var = sq * (1.f / 128.f) - mu * mu;
      const float rstd = rsqrtf(var + 1e-5f);
      float h0 = (x0 - mu) * rstd * g0c + b0c;
      float h1 = (x1 - mu) * rstd * g1c + b1c;
      h0 = 0.5f * h0 * (1.f + erff(h0 * 0.7071067811865475f));
      h1 = 0.5f * h1 * (1.f + erff(h1 * 0.7071067811865475f));
      float o0 = h0 * w2a.x + h1 * w2b.x;
      float o1 = h0 * w2a.y + h1 * w2b.y;
      float o2 = h0 * w2a.z + h1 * w2b.z;
      float o3 = h0 * w2a.w + h1 * w2b.w;
#pragma unroll
      for (int mm = 32; mm >= 1; mm >>= 1) {
        o0 += __shfl_xor(o0, mm, 64);
        o1 += __shfl_xor(o1, mm, 64);
        o2 += __shfl_xor(o2, mm, 64);
        o3 += __shfl_xor(o3, mm, 64);
      }
      if (lane == 0) {
        *(float4*)(out + (size_t)(b0 + r0l + r) * 4) =
            make_float4(o0 + cls_b2[0], o1 + cls_b2[1], o2 + cls_b2[2], o3 + cls_b2[3]);
      }
    }
  }
}

// ================= host =================
extern "C" void kernel_launch(void* const* d_in, const int* in_sizes, int n_in,
                              void* d_out, int out_size, void* d_ws, size_t ws_size,
                              hipStream_t stream) {
  const float* L_norm   = (const float*)d_in[0];
  const float* X_seq    = (const float*)d_in[1];
  const float* conv_w   = (const float*)d_in[2];
  const float* conv_b   = (const float*)d_in[3];
  const float* bn_gamma = (const float*)d_in[4];
  const float* bn_beta  = (const float*)d_in[5];
  const float* bn_mean  = (const float*)d_in[6];
  const float* bn_var   = (const float*)d_in[7];
  const float* gcn1_w   = (const float*)d_in[8];
  const float* gcn1_b   = (const float*)d_in[9];
  const float* mask1    = (const float*)d_in[10];
  const float* gcn2_w   = (const float*)d_in[11];
  const float* gcn2_b   = (const float*)d_in[12];
  const float* mask2    = (const float*)d_in[13];
  const float* beta2    = (const float*)d_in[14];
  const float* attn_w1  = (const float*)d_in[15];
  const float* attn_b1  = (const float*)d_in[16];
  const float* attn_w2  = (const float*)d_in[17];
  const float* attn_b2  = (const float*)d_in[18];
  const float* cls_w1   = (const float*)d_in[19];
  const float* cls_b1   = (const float*)d_in[20];
  const float* ln_gamma = (const float*)d_in[21];
  const float* ln_beta  = (const float*)d_in[22];
  const float* cls_w2   = (const float*)d_in[23];
  const float* cls_b2   = (const float*)d_in[24];

  char* ws = (char*)d_ws;
  float* wsf = (float*)d_ws;
  unsigned short* w1t  = (unsigned short*)(ws + OFF_W1T);
  unsigned short* cw1h = (unsigned short*)(ws + OFF_CW1H);
  unsigned short* cw1l = (unsigned short*)(ws + OFF_CW1L);

  // ctx hi/lo planes only (pots lives in LDS); 8192 B per batch
  long long avail = (long long)ws_size - (long long)OFF_CTX;
  int chunk = 4096;
  if (avail < 8192LL * 4096LL) {
    long long c = (avail > 0) ? (avail / 8192) : 64;
    if (c > 4096) c = 4096;
    c &= ~63LL;
    if (c < 64) c = 64;
    chunk = (int)c;
  }
  unsigned short* ctxh = (unsigned short*)(ws + OFF_CTX);
  unsigned short* ctxl = ctxh + (size_t)chunk * 2048;

  hipLaunchKernelGGL(k_prep, dim3(256), dim3(256), 0, stream,
                     mask1, mask2, conv_w, conv_b, bn_gamma, bn_beta, bn_mean, bn_var,
                     attn_w1, cls_w1, wsf, w1t, cw1h, cw1l);

  for (int b0 = 0; b0 < 4096; b0 += chunk) {
    int cur = 4096 - b0;
    if (cur > chunk) cur = chunk;
    hipLaunchKernelGGL(k_fused, dim3(cur), dim3(256), 0, stream,
                       L_norm, X_seq, gcn1_w, gcn1_b, gcn2_w, gcn2_b, beta2,
                       wsf, w1t, attn_b1, attn_w2, attn_b2, ctxh, ctxl, b0);
    hipLaunchKernelGGL(k_cls, dim3(cur / 16), dim3(512), 0, stream,
                       ctxh, ctxl, cw1h, cw1l, cls_b1, ln_gamma, ln_beta, cls_w2, cls_b2,
                       (float*)d_out, b0);
  }
}

// Round 11
// 487.259 us; speedup vs baseline: 1.3770x; 1.0182x over previous
//
#include <hip/hip_runtime.h>
#include <math.h>

// ---------------- workspace layout (bytes unless _F) ----------------
#define WS_M1_F    0           // 4096 f32
#define WS_M2_F    4096        // 4096 f32
#define WS_BNSC_F  8192        // 64 f32
#define WS_BNSH_F  8256        // 64 f32
#define WS_WT_F    8448        // 12288 f32 (conv_w transposed [ik][o])
#define OFF_W1T    83968       // u16[32*2048]  attn_w1^T fp16  -> +131072 = 215040
#define OFF_CW1H   215040      // u16[128*2048] cls_w1^T bf16-hi -> +524288 = 739328
#define OFF_CW1L   739328      // u16[128*2048] cls_w1^T bf16-lo -> +524288 = 1263616
#define OFF_CTX    1263616     // per-chunk ctx hi/lo planes (8192 B/batch)

typedef _Float16 v8h __attribute__((ext_vector_type(8)));
typedef short v8s __attribute__((ext_vector_type(8)));
typedef float v4f __attribute__((ext_vector_type(4)));
typedef float v16f __attribute__((ext_vector_type(16)));

__device__ __forceinline__ unsigned short f2h_u(float x) {
  _Float16 h = (_Float16)x;
  union { _Float16 h; unsigned short u; } v; v.h = h; return v.u;
}
__device__ __forceinline__ unsigned short bf16t(float x) {
  union { float f; unsigned int u; } v; v.f = x; return (unsigned short)(v.u >> 16);
}
__device__ __forceinline__ float bf16tof(unsigned short s) {
  union { unsigned int u; float f; } v; v.u = ((unsigned int)s) << 16; return v.f;
}

// ================= K1: prep (multi-block) =================
__global__ __launch_bounds__(256) void k_prep(
    const float* __restrict__ mask1, const float* __restrict__ mask2,
    const float* __restrict__ conv_w, const float* __restrict__ conv_b,
    const float* __restrict__ bn_gamma, const float* __restrict__ bn_beta,
    const float* __restrict__ bn_mean, const float* __restrict__ bn_var,
    const float* __restrict__ attn_w1, const float* __restrict__ cls_w1,
    float* __restrict__ wsf, unsigned short* __restrict__ w1t,
    unsigned short* __restrict__ cw1h, unsigned short* __restrict__ cw1l)
{
  const int gid = blockIdx.x * 256 + threadIdx.x;
  const int gsz = gridDim.x * 256;
  float* m1 = wsf + WS_M1_F;
  float* m2 = wsf + WS_M2_F;
  float* bnsc = wsf + WS_BNSC_F;
  float* bnsh = wsf + WS_BNSH_F;
  float* wT = wsf + WS_WT_F;
  for (int e = gid; e < 4096; e += gsz) {
    int i = e >> 6, j = e & 63;
    float s1 = mask1[e] + mask1[j * 64 + i];
    float s2 = mask2[e] + mask2[j * 64 + i];
    m1[e] = 0.5f / (1.f + expf(-s1));
    m2[e] = 0.5f / (1.f + expf(-s2));
  }
  for (int e = gid; e < 64; e += gsz) {
    float sc = bn_gamma[e] * rsqrtf(bn_var[e] + 1e-5f);
    bnsc[e] = sc;
    bnsh[e] = (conv_b[e] - bn_mean[e]) * sc + bn_beta[e];
  }
  for (int e = gid; e < 12288; e += gsz) {
    int o = e / 192, ik = e % 192;
    wT[ik * 64 + o] = conv_w[e];
  }
  for (int e = gid; e < 65536; e += gsz) {
    int n = e >> 11, i = e & 2047;
    w1t[e] = f2h_u(attn_w1[i * 32 + n]);
  }
  for (int e = gid; e < 262144; e += gsz) {
    int n = e >> 11, k = e & 2047;
    float x = cls_w1[k * 128 + n];
    unsigned short h = bf16t(x);
    cw1h[e] = h;
    cw1l[e] = bf16t(x - bf16tof(h));
  }
}

// ===== K2: fused conv+BN -> recurrence -> attention, one block per batch =====
// 256 threads (4 waves). LDS: pots_s 65536 B + smR 11776 B = 77312 B
// -> 2 blocks/CU. Row 15 of pots_s ZEROED at start (replay determinism).
// Phase A uses a TRANSPOSED, ZERO-PADDED x staging (xrawT[i][pad2+t], row
// stride 20 f32): the 4 consecutive timesteps per wave read their 6 taps as
// one ds_read_b128 + one ds_read_b64 broadcast instead of 11 scalar reads.
// Softmax-weight broadcast is register shuffles, NOT LDS (wbuf RAW race,
// rounds 6-8).
__global__ __launch_bounds__(256) void k_fused(
    const float* __restrict__ L_norm, const float* __restrict__ X_seq,
    const float* __restrict__ gcn1_w, const float* __restrict__ gcn1_b,
    const float* __restrict__ gcn2_w, const float* __restrict__ gcn2_b,
    const float* __restrict__ beta2p, const float* __restrict__ wsf,
    const unsigned short* __restrict__ w1t,
    const float* __restrict__ attn_b1, const float* __restrict__ attn_w2,
    const float* __restrict__ attn_b2,
    unsigned short* __restrict__ ctxh, unsigned short* __restrict__ ctxl,
    int b0)
{
  __shared__ __align__(16) unsigned short pots_s[16 * 2048];
  __shared__ __align__(16) char smR[11776];
  float* xcur = (float*)smR;                          // 960 f32   [0,3840)
  float* zp = (float*)(smR + 3840);                   // 128 f32   [3840,4352)
  unsigned short* spk1T = (unsigned short*)(smR + 4352); // 16*72 u16 [4352,6656)
  float* Z2f = (float*)(smR + 6656);                  // 64*20 f32 [6656,11776)

  const int tid = threadIdx.x;
  const int lane = tid & 63;
  const int wv = tid >> 6;
  const int b = b0 + blockIdx.x;

  const float* m1 = wsf + WS_M1_F;
  const float* m2 = wsf + WS_M2_F;

  // ---- phase A: conv + BN (xrawT staged in pots_s area, dead until t=1) ----
  {
    float* xrawT = (float*)pots_s;      // 64 rows x 20 f32 = 5120 B
    // zero the t-pad slots: left pad [0..1] and right pad [17]
    if (tid < 64) {
      xrawT[tid * 20 + 0] = 0.f;
      xrawT[tid * 20 + 1] = 0.f;
      xrawT[tid * 20 + 17] = 0.f;
    }
    for (int e = tid; e < 960; e += 256) {
      int t = e >> 6, i = e & 63;
      xrawT[i * 20 + 2 + t] = X_seq[(size_t)b * 960 + e];
    }
    // zero pots_s row 15 (feeds the discarded t=15 MFMA A-row): determinism
    *(uint4*)&pots_s[15 * 2048 + tid * 8] = make_uint4(0u, 0u, 0u, 0u);
    __syncthreads();
    const float* bnsc = wsf + WS_BNSC_F;
    const float* bnsh = wsf + WS_BNSH_F;
    const float* wT = wsf + WS_WT_F;
    const int o = lane;
    const int T = wv * 4;               // outputs t = T..T+3 (t=15 skipped)
    float a0 = 0.f, a1 = 0.f, a2 = 0.f, a3 = 0.f;
    for (int i = 0; i < 64; ++i) {
      const float w0 = wT[(3 * i + 0) * 64 + o];
      const float w1 = wT[(3 * i + 1) * 64 + o];
      const float w2 = wT[(3 * i + 2) * 64 + o];
      // padded taps: output t uses padded[t], padded[t+1], padded[t+2]
      float4 xq = *(const float4*)&xrawT[i * 20 + T];      // padded T..T+3
      float2 xr = *(const float2*)&xrawT[i * 20 + T + 4];  // padded T+4..T+5
      a0 += w0 * xq.x + w1 * xq.y + w2 * xq.z;
      a1 += w0 * xq.y + w1 * xq.z + w2 * xq.w;
      a2 += w0 * xq.z + w1 * xq.w + w2 * xr.x;
      if (T + 3 < 15) a3 += w0 * xq.w + w1 * xr.x + w2 * xr.y;
    }
    const float sc = bnsc[o], sh = bnsh[o];
    xcur[(T + 0) * 64 + o] = a0 * sc + sh;
    xcur[(T + 1) * 64 + o] = a1 * sc + sh;
    xcur[(T + 2) * 64 + o] = a2 * sc + sh;
    if (T + 3 < 15) xcur[(T + 3) * 64 + o] = a3 * sc + sh;
    __syncthreads();
  }

  // ---- phase B: register prep ----
  float L1h[32];
  const int kb1 = (wv & 1) * 32;
  if (wv >= 2) {
    const float* Lb = L_norm + (size_t)b * 4096 + lane * 64 + kb1;
    const float* mr = m1 + lane * 64 + kb1;
#pragma unroll
    for (int q4 = 0; q4 < 8; ++q4) {
      float4 lv = *(const float4*)(Lb + 4 * q4);
      float4 mv = *(const float4*)(mr + 4 * q4);
      L1h[4 * q4 + 0] = lv.x * mv.x;
      L1h[4 * q4 + 1] = lv.y * mv.y;
      L1h[4 * q4 + 2] = lv.z * mv.z;
      L1h[4 * q4 + 3] = lv.w * mv.w;
    }
  }

  v8s A_hi[2], A_lo[2];
  {
    const int irow = wv * 16 + (lane & 15);
    const int quad = (lane >> 4) & 3;
#pragma unroll
    for (int kb = 0; kb < 2; ++kb) {
      const float* Lb = L_norm + (size_t)b * 4096 + irow * 64 + kb * 32 + quad * 8;
      const float* mr = m2 + irow * 64 + kb * 32 + quad * 8;
      float4 la = *(const float4*)Lb, lb2 = *(const float4*)(Lb + 4);
      float4 ma = *(const float4*)mr, mb = *(const float4*)(mr + 4);
      float v[8] = { la.x * ma.x, la.y * ma.y, la.z * ma.z, la.w * ma.w,
                     lb2.x * mb.x, lb2.y * mb.y, lb2.z * mb.z, lb2.w * mb.w };
#pragma unroll
      for (int e = 0; e < 8; ++e) {
        unsigned short h = bf16t(v[e]);
        unsigned short l = bf16t(v[e] - bf16tof(h));
        A_hi[kb][e] = (short)h;
        A_lo[kb][e] = (short)l;
      }
    }
  }

  v8s W_hi, W_lo;
  {
    const int n = lane & 31;
    const int kh = (lane >> 5) & 1;
#pragma unroll
    for (int e = 0; e < 8; ++e) {
      float x = gcn2_w[(kh * 8 + e) * 32 + n];
      unsigned short h = bf16t(x);
      unsigned short l = bf16t(x - bf16tof(h));
      W_hi[e] = (short)h;
      W_lo[e] = (short)l;
    }
  }

  const float b2h = gcn2_b[lane & 31];
  const int np = tid >> 3;
  const int cp = tid & 7;
  float w1c[2], b1c[2];
#pragma unroll
  for (int d = 0; d < 2; ++d) { w1c[d] = gcn1_w[2 * cp + d]; b1c[d] = gcn1_b[2 * cp + d]; }
  const float beta2 = beta2p[0];

  float mem_t = 0.f;
  float mg1[4] = {0.f, 0.f, 0.f, 0.f};
  v16f mg2;
#pragma unroll
  for (int r = 0; r < 16; ++r) mg2[r] = 0.f;

  auto stage_b = [&](int tm1) {
    const int m = lane & 31;
    const int half = lane >> 5;
    const float* zr = Z2f + (wv * 32 + m) * 20 + half * 8;
    float4 za = *(const float4*)zr;
    float4 zb = *(const float4*)(zr + 4);
    float vv[8] = {za.x, za.y, za.z, za.w, zb.x, zb.y, zb.z, zb.w};
    v8s Ah, Al;
#pragma unroll
    for (int e = 0; e < 8; ++e) {
      unsigned short h = bf16t(vv[e]);
      unsigned short l = bf16t(vv[e] - bf16tof(h));
      Ah[e] = (short)h;
      Al[e] = (short)l;
    }
    v16f acc;
#pragma unroll
    for (int r = 0; r < 16; ++r) {
      float rs = (mg2[r] > 1.f) ? 1.f : 0.f;
      acc[r] = fmaf(beta2, mg2[r], b2h - rs);
    }
    acc = __builtin_amdgcn_mfma_f32_32x32x16_bf16(Ah, W_hi, acc, 0, 0, 0);
    acc = __builtin_amdgcn_mfma_f32_32x32x16_bf16(Al, W_hi, acc, 0, 0, 0);
    acc = __builtin_amdgcn_mfma_f32_32x32x16_bf16(Ah, W_lo, acc, 0, 0, 0);
    mg2 = acc;
    const int xorv = (tm1 & 7) << 3;
    const int base = tm1 * 2048 + m;
#pragma unroll
    for (int r = 0; r < 16; ++r) {
      int i = wv * 32 + (r & 3) + 8 * (r >> 2) + 4 * half;
      pots_s[(base + i * 32) ^ xorv] = f2h_u(acc[r]);
    }
  };

  // ---- phase C: 15-step recurrence ----
  for (int t = 0; t < 15; ++t) {
    if (wv >= 2) {
      float xc = xcur[t * 64 + lane];
      float rs = (mem_t > 1.f) ? 1.f : 0.f;
      mem_t = 0.9f * mem_t + xc - rs;
      float sp = (mem_t > 1.f) ? 1.f : 0.f;
      int spi = __float_as_int(sp);
      float zh = 0.f;
#pragma unroll
      for (int k = 0; k < 32; ++k) {
        float s = __int_as_float(__builtin_amdgcn_readlane(spi, kb1 + k));
        zh = fmaf(s, L1h[k], zh);
      }
      zp[(wv & 1) * 64 + lane] = zh;
    } else if (t > 0) {
      stage_b(t - 1);
    }
    __syncthreads();
    {
      float2 q0 = *(const float2*)&zp[2 * np];
      float2 q1 = *(const float2*)&zp[64 + 2 * np];
      float z0 = q0.x + q1.x;
      float z1v = q0.y + q1.y;
#pragma unroll
      for (int d = 0; d < 2; ++d) {
        float cur0 = fmaf(z0, w1c[d], b1c[d]);
        float rs0 = (mg1[d * 2 + 0] > 1.f) ? 1.f : 0.f;
        mg1[d * 2 + 0] = 0.85f * mg1[d * 2 + 0] + cur0 - rs0;
        unsigned int bits0 = (mg1[d * 2 + 0] > 1.f) ? 0x3F80u : 0u;
        float cur1 = fmaf(z1v, w1c[d], b1c[d]);
        float rs1 = (mg1[d * 2 + 1] > 1.f) ? 1.f : 0.f;
        mg1[d * 2 + 1] = 0.85f * mg1[d * 2 + 1] + cur1 - rs1;
        unsigned int bits1 = (mg1[d * 2 + 1] > 1.f) ? 0x3F80u : 0u;
        *(unsigned int*)&spk1T[(2 * cp + d) * 72 + 2 * np] = bits0 | (bits1 << 16);
      }
    }
    __syncthreads();
    {
      const int c = lane & 15;
      const int quad = (lane >> 4) & 3;
      const unsigned short* bp = spk1T + c * 72 + quad * 8;
      v8s B0 = *(const v8s*)(bp);
      v8s B1 = *(const v8s*)(bp + 32);
      v4f acc = {0.f, 0.f, 0.f, 0.f};
      acc = __builtin_amdgcn_mfma_f32_16x16x32_bf16(A_hi[0], B0, acc, 0, 0, 0);
      acc = __builtin_amdgcn_mfma_f32_16x16x32_bf16(A_lo[0], B0, acc, 0, 0, 0);
      acc = __builtin_amdgcn_mfma_f32_16x16x32_bf16(A_hi[1], B1, acc, 0, 0, 0);
      acc = __builtin_amdgcn_mfma_f32_16x16x32_bf16(A_lo[1], B1, acc, 0, 0, 0);
      const int r0 = wv * 16 + quad * 4;
#pragma unroll
      for (int r = 0; r < 4; ++r) Z2f[(r0 + r) * 20 + c] = acc[r];
    }
    __syncthreads();
  }
  if (wv < 2) stage_b(14);
  __syncthreads();   // pots_s complete; smR free for sred overlay

  // ---- phase D: attention (scores + softmax + ctx) from LDS pots ----
  float* sred = (float*)smR;            // 8*256 f32 (overlays xcur/zp/spk1T/Z2f)
  const int m = lane & 15;
  const int quad = lane >> 4;
  const int koff = quad * 8;

  v4f a0 = {0.f, 0.f, 0.f, 0.f}, a1 = {0.f, 0.f, 0.f, 0.f};
  {
    const int axor = (m & 7) << 3;      // row 15 zeroed -> deterministic
    const int abase = m * 2048 + koff;
    const unsigned short* B0p = w1t + (size_t)m * 2048 + koff;
    const unsigned short* B1p = w1t + (size_t)(m + 16) * 2048 + koff;
#pragma unroll 4
    for (int c = wv * 16; c < wv * 16 + 16; ++c) {
      v8h A = *(const v8h*)(pots_s + ((abase + c * 32) ^ axor));
      v8h B0 = *(const v8h*)(B0p + c * 32);
      v8h B1 = *(const v8h*)(B1p + c * 32);
      a0 = __builtin_amdgcn_mfma_f32_16x16x32_f16(A, B0, a0, 0, 0, 0);
      a1 = __builtin_amdgcn_mfma_f32_16x16x32_f16(A, B1, a1, 0, 0, 0);
    }
  }
#pragma unroll
  for (int j = 0; j < 4; ++j) {
    sred[j * 256 + tid] = a0[j];
    sred[(j + 4) * 256 + tid] = a1[j];
  }
  __syncthreads();
  float s0[4], s1[4];
#pragma unroll
  for (int j = 0; j < 4; ++j) {
    s0[j] = sred[j * 256 + 0 * 64 + lane] + sred[j * 256 + 1 * 64 + lane]
          + sred[j * 256 + 2 * 64 + lane] + sred[j * 256 + 3 * 64 + lane];
    s1[j] = sred[(j + 4) * 256 + 0 * 64 + lane] + sred[(j + 4) * 256 + 1 * 64 + lane]
          + sred[(j + 4) * 256 + 2 * 64 + lane] + sred[(j + 4) * 256 + 3 * 64 + lane];
  }
  float wlar[16];
  {
    const int n = m;
    const float b1a = attn_b1[n], b1b = attn_b1[n + 16];
    const float w2a = attn_w2[n], w2b = attn_w2[n + 16];
    const float b2 = attn_b2[0];
    float sc[4];
#pragma unroll
    for (int r = 0; r < 4; ++r) {
      float v = tanhf(s0[r] + b1a) * w2a + tanhf(s1[r] + b1b) * w2b;
      v += __shfl_xor(v, 1, 64);
      v += __shfl_xor(v, 2, 64);
      v += __shfl_xor(v, 4, 64);
      v += __shfl_xor(v, 8, 64);
      sc[r] = v + b2;
    }
    float mx = -1e30f;
#pragma unroll
    for (int r = 0; r < 4; ++r) if (quad * 4 + r < 15) mx = fmaxf(mx, sc[r]);
    mx = fmaxf(mx, __shfl_xor(mx, 16, 64));
    mx = fmaxf(mx, __shfl_xor(mx, 32, 64));
    float e[4], den = 0.f;
#pragma unroll
    for (int r = 0; r < 4; ++r) {
      e[r] = (quad * 4 + r < 15) ? expf(sc[r] - mx) : 0.f;
      den += e[r];
    }
    den += __shfl_xor(den, 16, 64);
    den += __shfl_xor(den, 32, 64);
    const float inv = 1.f / den;
    // Broadcast each quad-group's e[0..3] via register shuffles (race-free).
#pragma unroll
    for (int q4 = 0; q4 < 4; ++q4) {
#pragma unroll
      for (int r = 0; r < 4; ++r) {
        wlar[q4 * 4 + r] = __shfl(e[r], q4 * 16, 64) * inv;
      }
    }
  }
  // ctx = sum_t w_t * pots[t] (swizzled LDS rows, conflict-free)
  float cv[8] = {0.f, 0.f, 0.f, 0.f, 0.f, 0.f, 0.f, 0.f};
#pragma unroll
  for (int t = 0; t < 15; ++t) {
    const int idx = (t * 2048 + tid * 8) ^ ((t & 7) << 3);
    v8h pv = *(const v8h*)(pots_s + idx);
    const float w = wlar[t];
#pragma unroll
    for (int j = 0; j < 8; ++j) cv[j] = fmaf(w, (float)pv[j], cv[j]);
  }
  unsigned short hv[8], lv[8];
#pragma unroll
  for (int j = 0; j < 8; ++j) {
    unsigned short h = bf16t(cv[j]);
    hv[j] = h;
    lv[j] = bf16t(cv[j] - bf16tof(h));
  }
  *(uint4*)(ctxh + (size_t)blockIdx.x * 2048 + tid * 8) = *(const uint4*)hv;
  *(uint4*)(ctxl + (size_t)blockIdx.x * 2048 + tid * 8) = *(const uint4*)lv;
}

// ================= K4: classifier, MFMA bf16 hi/lo, 8-wave K-split =========
__global__ __launch_bounds__(512) void k_cls(
    const unsigned short* __restrict__ ctxh, const unsigned short* __restrict__ ctxl,
    const unsigned short* __restrict__ cw1h, const unsigned short* __restrict__ cw1l,
    const float* __restrict__ cls_b1,
    const float* __restrict__ ln_g, const float* __restrict__ ln_b,
    const float* __restrict__ cls_w2, const float* __restrict__ cls_b2,
    float* __restrict__ out, int b0)
{
  __shared__ float hbuf[16 * 132];       // 8448 B
  __shared__ __align__(16) float pred[256 * 8];  // 8192 B partials (waves 4-7)
  const int tid = threadIdx.x;
  const int lane = tid & 63;
  const int wv = tid >> 6;      // 0..7
  const int wq = wv & 3;        // n-group
  const int kh = wv >> 2;       // K-half
  const int m = lane & 15;
  const int quad = lane >> 4;
  const int koff = quad * 8;
  const int r0l = blockIdx.x * 16;

  v4f a0 = {0.f, 0.f, 0.f, 0.f}, a1 = {0.f, 0.f, 0.f, 0.f};
  {
    const unsigned short* Ah = ctxh + (size_t)(r0l + m) * 2048;
    const unsigned short* Al = ctxl + (size_t)(r0l + m) * 2048;
    const int n0 = wq * 32 + m;
    const unsigned short* B0h = cw1h + (size_t)n0 * 2048;
    const unsigned short* B0l = cw1l + (size_t)n0 * 2048;
    const unsigned short* B1h = cw1h + (size_t)(n0 + 16) * 2048;
    const unsigned short* B1l = cw1l + (size_t)(n0 + 16) * 2048;
    const int kc0 = kh * 32;
#pragma unroll 4
    for (int kc = kc0; kc < kc0 + 32; ++kc) {
      const int kb = kc * 32 + koff;
      v8s vAh = *(const v8s*)(Ah + kb);
      v8s vAl = *(const v8s*)(Al + kb);
      v8s vB0h = *(const v8s*)(B0h + kb);
      v8s vB0l = *(const v8s*)(B0l + kb);
      v8s vB1h = *(const v8s*)(B1h + kb);
      v8s vB1l = *(const v8s*)(B1l + kb);
      a0 = __builtin_amdgcn_mfma_f32_16x16x32_bf16(vAh, vB0h, a0, 0, 0, 0);
      a0 = __builtin_amdgcn_mfma_f32_16x16x32_bf16(vAl, vB0h, a0, 0, 0, 0);
      a0 = __builtin_amdgcn_mfma_f32_16x16x32_bf16(vAh, vB0l, a0, 0, 0, 0);
      a1 = __builtin_amdgcn_mfma_f32_16x16x32_bf16(vAh, vB1h, a1, 0, 0, 0);
      a1 = __builtin_amdgcn_mfma_f32_16x16x32_bf16(vAl, vB1h, a1, 0, 0, 0);
      a1 = __builtin_amdgcn_mfma_f32_16x16x32_bf16(vAh, vB1l, a1, 0, 0, 0);
    }
  }
  // K-halves combine: waves 4-7 deposit, barrier, waves 0-3 add.
  if (kh == 1) {
    float* p = pred + (size_t)(wq * 64 + lane) * 8;
    *(v4f*)p = a0;
    *(v4f*)(p + 4) = a1;
  }
  __syncthreads();
  if (kh == 0) {
    const float* p = pred + (size_t)(wq * 64 + lane) * 8;
    v4f b0v = *(const v4f*)p;
    v4f b1v = *(const v4f*)(p + 4);
#pragma unroll
    for (int r = 0; r < 4; ++r) { a0[r] += b0v[r]; a1[r] += b1v[r]; }
    const int n0 = wq * 32 + m;
    const float bb0 = cls_b1[n0], bb1 = cls_b1[n0 + 16];
#pragma unroll
    for (int r = 0; r < 4; ++r) {
      const int row = quad * 4 + r;
      hbuf[row * 132 + n0] = a0[r] + bb0;
      hbuf[row * 132 + n0 + 16] = a1[r] + bb1;
    }
  }
  __syncthreads();
  if (kh == 0) {
    const float g0c = ln_g[lane], g1c = ln_g[lane + 64];
    const float b0c = ln_b[lane], b1c = ln_b[lane + 64];
    const float4 w2a = *(const float4*)(cls_w2 + lane * 4);
    const float4 w2b = *(const float4*)(cls_w2 + (lane + 64) * 4);
#pragma unroll
    for (int rr = 0; rr < 4; ++rr) {
      const int r = wq * 4 + rr;
      const float x0 = hbuf[r * 132 + lane];
      const float x1 = hbuf[r * 132 + 64 + lane];
      float s = x0 + x1, sq = x0 * x0 + x1 * x1;
#pragma unroll
      for (int mm = 32; mm >= 1; mm >>= 1) {
        s += __shfl_xor(s, mm, 64);
        sq += __shfl_xor(sq, mm, 64);
      }
      const float mu = s * (1.f / 128.f);
      const float var = sq * (1.f / 128.f) - mu * mu;
      const float rstd = rsqrtf(var + 1e-5f);
      float h0 = (x0 - mu) * rstd * g0c + b0c;
      float h1 = (x1 - mu) * rstd * g1c + b1c;
      h0 = 0.5f * h0 * (1.f + erff(h0 * 0.7071067811865475f));
      h1 = 0.5f * h1 * (1.f + erff(h1 * 0.7071067811865475f));
      float o0 = h0 * w2a.x + h1 * w2b.x;
      float o1 = h0 * w2a.y + h1 * w2b.y;
      float o2 = h0 * w2a.z + h1 * w2b.z;
      float o3 = h0 * w2a.w + h1 * w2b.w;
#pragma unroll
      for (int mm = 32; mm >= 1; mm >>= 1) {
        o0 += __shfl_xor(o0, mm, 64);
        o1 += __shfl_xor(o1, mm, 64);
        o2 += __shfl_xor(o2, mm, 64);
        o3 += __shfl_xor(o3, mm, 64);
      }
      if (lane == 0) {
        *(float4*)(out + (size_t)(b0 + r0l + r) * 4) =
            make_float4(o0 + cls_b2[0], o1 + cls_b2[1], o2 + cls_b2[2], o3 + cls_b2[3]);
      }
    }
  }
}

// ================= host =================
extern "C" void kernel_launch(void* const* d_in, const int* in_sizes, int n_in,
                              void* d_out, int out_size, void* d_ws, size_t ws_size,
                              hipStream_t stream) {
  const float* L_norm   = (const float*)d_in[0];
  const float* X_seq    = (const float*)d_in[1];
  const float* conv_w   = (const float*)d_in[2];
  const float* conv_b   = (const float*)d_in[3];
  const float* bn_gamma = (const float*)d_in[4];
  const float* bn_beta  = (const float*)d_in[5];
  const float* bn_mean  = (const float*)d_in[6];
  const float* bn_var   = (const float*)d_in[7];
  const float* gcn1_w   = (const float*)d_in[8];
  const float* gcn1_b   = (const float*)d_in[9];
  const float* mask1    = (const float*)d_in[10];
  const float* gcn2_w   = (const float*)d_in[11];
  const float* gcn2_b   = (const float*)d_in[12];
  const float* mask2    = (const float*)d_in[13];
  const float* beta2    = (const float*)d_in[14];
  const float* attn_w1  = (const float*)d_in[15];
  const float* attn_b1  = (const float*)d_in[16];
  const float* attn_w2  = (const float*)d_in[17];
  const float* attn_b2  = (const float*)d_in[18];
  const float* cls_w1   = (const float*)d_in[19];
  const float* cls_b1   = (const float*)d_in[20];
  const float* ln_gamma = (const float*)d_in[21];
  const float* ln_beta  = (const float*)d_in[22];
  const float* cls_w2   = (const float*)d_in[23];
  const float* cls_b2   = (const float*)d_in[24];

  char* ws = (char*)d_ws;
  float* wsf = (float*)d_ws;
  unsigned short* w1t  = (unsigned short*)(ws + OFF_W1T);
  unsigned short* cw1h = (unsigned short*)(ws + OFF_CW1H);
  unsigned short* cw1l = (unsigned short*)(ws + OFF_CW1L);

  // ctx hi/lo planes only (pots lives in LDS); 8192 B per batch
  long long avail = (long long)ws_size - (long long)OFF_CTX;
  int chunk = 4096;
  if (avail < 8192LL * 4096LL) {
    long long c = (avail > 0) ? (avail / 8192) : 64;
    if (c > 4096) c = 4096;
    c &= ~63LL;
    if (c < 64) c = 64;
    chunk = (int)c;
  }
  unsigned short* ctxh = (unsigned short*)(ws + OFF_CTX);
  unsigned short* ctxl = ctxh + (size_t)chunk * 2048;

  hipLaunchKernelGGL(k_prep, dim3(256), dim3(256), 0, stream,
                     mask1, mask2, conv_w, conv_b, bn_gamma, bn_beta, bn_mean, bn_var,
                     attn_w1, cls_w1, wsf, w1t, cw1h, cw1l);

  for (int b0 = 0; b0 < 4096; b0 += chunk) {
    int cur = 4096 - b0;
    if (cur > chunk) cur = chunk;
    hipLaunchKernelGGL(k_fused, dim3(cur), dim3(256), 0, stream,
                       L_norm, X_seq, gcn1_w, gcn1_b, gcn2_w, gcn2_b, beta2,
                       wsf, w1t, attn_b1, attn_w2, attn_b2, ctxh, ctxl, b0);
    hipLaunchKernelGGL(k_cls, dim3(cur / 16), dim3(512), 0, stream,
                       ctxh, ctxl, cw1h, cw1l, cls_b1, ln_gamma, ln_beta, cls_w2, cls_b2,
                       (float*)d_out, b0);
  }
}